// Round 2
// baseline (247.994 us; speedup 1.0000x reference)
//
#include <hip/hip_runtime.h>
#include <math.h>

#define Vc 5
#define Cc 32
#define Gc 8
#define Dc 32
#define Hc 192
#define Wc 192
#define HWc (Hc*Wc)
#define NSRC (Vc-1)

// output offsets (floats)
#define OFF_DEPTH  0
#define OFF_CONF   (HWc)
#define OFF_ATTN   (2*HWc)
#define OFF_EST    (OFF_ATTN + Dc*HWc)
#define OFF_SW     (OFF_EST + 3*HWc)
#define OFF_WEIGHT (OFF_SW + HWc)
#define OFF_NVAL   (OFF_WEIGHT + NSRC*HWc)
#define OFF_MIN    (OFF_NVAL + Dc*HWc)
#define OFF_MAX    (OFF_MIN + HWc)

// ws layout (floats):
//   [0]=hmin bits(uint) [1]=hmax bits(uint)
//   [2 + i*15]: rot(9), trans(3), norv(3)
//   [64 + k*Cc*HWc]: channels-last images, k=0 ref, k=1..4 src, k=5 depth
#define T_OFF 64

__device__ void inv4(const float* A, float* out) {
    float M[4][8];
    for (int r = 0; r < 4; r++) {
        for (int c = 0; c < 4; c++) { M[r][c] = A[r*4+c]; M[r][c+4] = (r == c) ? 1.f : 0.f; }
    }
    for (int col = 0; col < 4; col++) {
        int piv = col; float best = fabsf(M[col][col]);
        for (int r = col+1; r < 4; r++) { float v = fabsf(M[r][col]); if (v > best) { best = v; piv = r; } }
        if (piv != col) for (int c = 0; c < 8; c++) { float t = M[col][c]; M[col][c] = M[piv][c]; M[piv][c] = t; }
        float inv = 1.f / M[col][col];
        for (int c = 0; c < 8; c++) M[col][c] *= inv;
        for (int r = 0; r < 4; r++) {
            if (r == col) continue;
            float f = M[r][col];
            for (int c = 0; c < 8; c++) M[r][c] -= f * M[col][c];
        }
    }
    for (int r = 0; r < 4; r++) for (int c = 0; c < 4; c++) out[r*4+c] = M[r][c+4];
}

__device__ void inv3(const float* A, float* out) {
    float a=A[0],b=A[1],c=A[2],d=A[3],e=A[4],f=A[5],g=A[6],h=A[7],i=A[8];
    float det = a*(e*i-f*h) - b*(d*i-f*g) + c*(d*h-e*g);
    float id = 1.f/det;
    out[0]=(e*i-f*h)*id; out[1]=(c*h-b*i)*id; out[2]=(b*f-c*e)*id;
    out[3]=(f*g-d*i)*id; out[4]=(a*i-c*g)*id; out[5]=(c*d-a*f)*id;
    out[6]=(d*h-e*g)*id; out[7]=(b*g-a*h)*id; out[8]=(a*e-b*d)*id;
}

__global__ void setup_kernel(const float* __restrict__ rotation,
                             const float* __restrict__ proj,
                             float* __restrict__ wsf) {
    if (threadIdx.x != 0 || blockIdx.x != 0) return;
    unsigned int* wsu = (unsigned int*)wsf;
    wsu[0] = 0x7F800000u;  // +inf  (hmin)
    wsu[1] = 0u;           // 0.0   (hmax; depths positive)

    float refE[16], refK[16], refNew[16], invRef[16];
    for (int k = 0; k < 16; k++) { refE[k] = proj[k]; refK[k] = proj[16+k]; }
    for (int k = 0; k < 16; k++) refNew[k] = refE[k];
    for (int r = 0; r < 3; r++) for (int c = 0; c < 4; c++) {
        float s = 0.f;
        for (int k = 0; k < 3; k++) s += refK[r*4+k] * refE[k*4+c];
        refNew[r*4+c] = s;
    }
    inv4(refNew, invRef);
    float invR0[9];
    inv3(rotation, invR0);

    for (int i = 0; i < NSRC; i++) {
        const float* E = proj + (i+1)*32;
        const float* K = proj + (i+1)*32 + 16;
        float sNew[16];
        for (int k = 0; k < 16; k++) sNew[k] = E[k];
        for (int r = 0; r < 3; r++) for (int c = 0; c < 4; c++) {
            float s = 0.f;
            for (int k = 0; k < 3; k++) s += K[r*4+k] * E[k*4+c];
            sNew[r*4+c] = s;
        }
        float P[16];
        for (int r = 0; r < 4; r++) for (int c = 0; c < 4; c++) {
            float s = 0.f;
            for (int k = 0; k < 4; k++) s += sNew[r*4+k] * invRef[k*4+c];
            P[r*4+c] = s;
        }
        float* o = wsf + 2 + i*15;
        for (int r = 0; r < 3; r++) for (int c = 0; c < 3; c++) o[r*3+c] = P[r*4+c];
        for (int r = 0; r < 3; r++) o[9+r] = P[r*4+3];
        const float* Ri = rotation + (i+1)*9;
        for (int c = 0; c < 3; c++) {
            float s = 0.f;
            for (int k = 0; k < 3; k++) s += Ri[2*3+k] * invR0[k*3+c];
            o[12+c] = s;
        }
    }
}

__global__ __launch_bounds__(256)
void minmax_kernel(const float* __restrict__ depth, unsigned int* __restrict__ wsu) {
    const int tid = blockIdx.x * blockDim.x + threadIdx.x;
    const int stride = gridDim.x * blockDim.x;
    const int n4 = (Dc*HWc) / 4;
    const float4* d4 = (const float4*)depth;
    float mn = __uint_as_float(0x7F800000u);
    float mx = 0.f;
    for (int idx = tid; idx < n4; idx += stride) {
        float4 v = d4[idx];
        mn = fminf(mn, fminf(fminf(v.x, v.y), fminf(v.z, v.w)));
        mx = fmaxf(mx, fmaxf(fmaxf(v.x, v.y), fmaxf(v.z, v.w)));
    }
    for (int off = 32; off; off >>= 1) {
        mn = fminf(mn, __shfl_xor(mn, off));
        mx = fmaxf(mx, __shfl_xor(mx, off));
    }
    __shared__ float smn[4], smx[4];
    const int w = threadIdx.x >> 6;
    if ((threadIdx.x & 63) == 0) { smn[w] = mn; smx[w] = mx; }
    __syncthreads();
    if (threadIdx.x == 0) {
        for (int i = 1; i < 4; i++) { mn = fminf(mn, smn[i]); mx = fmaxf(mx, smx[i]); }
        atomicMin(&wsu[0], __float_as_uint(mn));
        atomicMax(&wsu[1], __float_as_uint(mx));
    }
}

// [C][HW] -> [HW][C] channels-last transpose
__global__ __launch_bounds__(256)
void transpose_kernel(const float* __restrict__ ref,
                      const float* __restrict__ src,
                      const float* __restrict__ depth,
                      float* __restrict__ wsT) {
    const int img = blockIdx.y;          // 0..5
    const int p0  = blockIdx.x * 64;
    const float* in = (img == 0) ? ref
                    : (img <= NSRC) ? (src + (size_t)(img-1)*Cc*HWc)
                    : depth;
    float* outp = wsT + (size_t)img * Cc * HWc;
    __shared__ float tile[Cc][64+1];
    const int t = threadIdx.x;
#pragma unroll
    for (int k = 0; k < 8; k++) {
        const int c = (t >> 6) + k*4;
        const int p = t & 63;
        tile[c][p] = in[(size_t)c*HWc + p0 + p];
    }
    __syncthreads();
#pragma unroll
    for (int k = 0; k < 8; k++) {
        const int c = t & 31;
        const int p = (t >> 5) + k*8;
        outp[(size_t)(p0 + p)*Cc + c] = tile[c][p];
    }
}

// Bilinear weight + pre-scaled tap-offset computation for one (pix, d, view).
// rcp + one Newton step (~0.5 ulp) instead of the IEEE divide expansion.
__device__ __forceinline__ void compute_wo(float fxp, float fyp, const float* __restrict__ Wv,
                                           float dep, float4* wout, int4* oout) {
    const float b0 = Wv[0]*fxp + Wv[1]*fyp + Wv[2];
    const float b1 = Wv[3]*fxp + Wv[4]*fyp + Wv[5];
    const float b2 = Wv[6]*fxp + Wv[7]*fyp + Wv[8];
    float z = fmaf(b2, dep, Wv[11]);
    if (z == 0.f) z = 1e-9f;
    float rz = __builtin_amdgcn_rcpf(z);
    rz = rz * (2.f - z * rz);                 // Newton refine
    const float px = fmaf(b0, dep, Wv[9])  * rz;
    const float py = fmaf(b1, dep, Wv[10]) * rz;

    const float fx0 = floorf(px), fy0 = floorf(py);
    const float wx = px - fx0, wy = py - fy0;
    const float fx1 = fx0 + 1.f, fy1 = fy0 + 1.f;
    const bool ix0 = (fx0 >= 0.f) && (fx0 <= (float)(Wc-1));
    const bool ix1 = (fx1 >= 0.f) && (fx1 <= (float)(Wc-1));
    const bool iy0 = (fy0 >= 0.f) && (fy0 <= (float)(Hc-1));
    const bool iy1 = (fy1 >= 0.f) && (fy1 <= (float)(Hc-1));
    const float w00 = (1.f-wx)*(1.f-wy) * ((ix0 && iy0) ? 1.f : 0.f);
    const float w10 = wx*(1.f-wy)       * ((ix1 && iy0) ? 1.f : 0.f);
    const float w01 = (1.f-wx)*wy       * ((ix0 && iy1) ? 1.f : 0.f);
    const float w11 = wx*wy             * ((ix1 && iy1) ? 1.f : 0.f);
    const int xi0 = (int)fminf(fmaxf(fx0, 0.f), (float)(Wc-1));
    const int xi1 = (int)fminf(fmaxf(fx1, 0.f), (float)(Wc-1));
    const int yi0 = (int)fminf(fmaxf(fy0, 0.f), (float)(Hc-1));
    const int yi1 = (int)fminf(fmaxf(fy1, 0.f), (float)(Hc-1));
    *wout = make_float4(w00, w10, w01, w11);
    *oout = make_int4((yi0*Wc + xi0)*8, (yi0*Wc + xi1)*8,
                      (yi1*Wc + xi0)*8, (yi1*Wc + xi1)*8);   // float4 units
}

// Channels-last main kernel, weight-phase split + double-buffered pipeline.
// Lane map: g = t&7, d = t>>3. Wave0 (t<32, one lane per d) computes bilinear
// weights/offsets for the NEXT view during the softmax phase; all 256 threads
// then only do LDS-broadcast reads + 4 float4 gathers + blend-dot.
__global__ __launch_bounds__(256)
void main_kernel_t(const float* __restrict__ normal_plane,
                   const float* __restrict__ w_reg,
                   const float* __restrict__ w_norm,
                   const float* __restrict__ wsf,
                   float* __restrict__ out) {
    // bijective XCD swizzle: consecutive pix co-resident per XCD -> partial
    // output-line writes merge in that XCD's L2 (WRITE_SIZE was 8x inflated)
    const int bid = blockIdx.x;
    const int pix = (bid & 7) * (HWc/8) + (bid >> 3);
    const int t = threadIdx.x;
    const int g = t & 7;
    const int d = t >> 3;
    const int lane = t & 63;
    const float fxp = (float)(pix % Wc);
    const float fyp = (float)(pix / Wc);

    const float4* refT  = (const float4*)(wsf + T_OFF);
    const float4* srcT0 = (const float4*)(wsf + T_OFF + Cc*HWc);
    const float*  depT  = wsf + T_OFF + (size_t)5*Cc*HWc;

    __shared__ float4 s_wt[2][Dc];
    __shared__ int4   s_of[2][Dc];
    __shared__ float s_sd[Dc];
    __shared__ float s_val[Dc];
    __shared__ float s_w[Dc];

    float4 rv = refT[pix*8 + g];
    rv.x *= 0.25f; rv.y *= 0.25f; rv.z *= 0.25f; rv.w *= 0.25f;  // fold mean(C//G)
    const float np0 = normal_plane[0*HWc + pix];
    const float np1 = normal_plane[1*HWc + pix];
    const float np2 = normal_plane[2*HWc + pix];
    const float depth_d = depT[(size_t)pix*Dc + d];
    const float depw    = depT[(size_t)pix*Dc + (t & 31)];  // wave0 weight-phase depth
    const float wreg_g = w_reg[g];

    // per-view src weights (uniform over threads)
    float srcw[NSRC];
#pragma unroll
    for (int i = 0; i < NSRC; i++) {
        const float* Wv = wsf + 2 + i*15;
        srcw[i] = fmaxf(np0*Wv[12] + np1*Wv[13] + np2*Wv[14], 0.f) + 0.01f;
    }

    // prologue: weights for view 0
    if (t < 32) compute_wo(fxp, fyp, wsf + 2, depw, &s_wt[0][t], &s_of[0][t]);
    __syncthreads();

    float acc_cor = 0.f;
    float cws_acc = 1e-8f;
    float sumw_acc = 1e-8f;
    float nval_acc = 0.f;

#pragma unroll
    for (int i = 0; i < NSRC; i++) {
        const int buf = i & 1;
        // ---- phase 2: gather + blend-dot (all threads) ----
        const float4 wv = s_wt[buf][d];
        const int4   ov = s_of[buf][d];
        const float4* sp = srcT0 + (size_t)i*HWc*8;
        const float4 v00 = sp[ov.x + g];
        const float4 v10 = sp[ov.y + g];
        const float4 v01 = sp[ov.z + g];
        const float4 v11 = sp[ov.w + g];
        const float bx = wv.x*v00.x + wv.y*v10.x + wv.z*v01.x + wv.w*v11.x;
        const float by = wv.x*v00.y + wv.y*v10.y + wv.z*v01.y + wv.w*v11.y;
        const float bz = wv.x*v00.z + wv.y*v10.z + wv.z*v01.z + wv.w*v11.z;
        const float bw = wv.x*v00.w + wv.y*v10.w + wv.z*v01.w + wv.w*v11.w;
        const float corfeat = bx*rv.x + by*rv.y + bz*rv.z + bw*rv.w;

        float sd = corfeat;
        sd += __shfl_xor(sd, 1);
        sd += __shfl_xor(sd, 2);
        sd += __shfl_xor(sd, 4);

        const float c0 = __shfl(bx, lane & ~7);   // channel-0 blend
        const float valid = (c0 != 0.f) ? 1.f : 0.f;

        if (g == 0) { s_sd[d] = sd; s_val[d] = valid; }
        __syncthreads();

        // ---- phase 3 (wave0): softmax over d + sims + NEXT view's weights ----
        if (t < 32) {
            const float u = s_sd[t];
            float m = u;
            for (int off = 1; off < 32; off <<= 1) m = fmaxf(m, __shfl_xor(m, off));
            const float e = __expf(u - m);
            float se = e;
            for (int off = 1; off < 32; off <<= 1) se += __shfl_xor(se, off);
            float rse = __builtin_amdgcn_rcpf(se);
            rse = rse * (2.f - se * rse);
            s_w[t] = e * rse * 0.17677669529663687f;  // softmax / sqrt(C)

            float ss = srcw[i] * s_val[t];
            for (int off = 1; off < 32; off <<= 1) ss += __shfl_xor(ss, off);
            if (t == 0) out[OFF_WEIGHT + i*HWc + pix] = ss * (1.f/32.f);

            if (i + 1 < NSRC)
                compute_wo(fxp, fyp, wsf + 2 + (i+1)*15, depw,
                           &s_wt[buf^1][t], &s_of[buf^1][t]);
        }
        __syncthreads();

        // ---- phase 4: accumulate (all threads) ----
        const float cor_w = s_w[d];
        const float sw = srcw[i] * valid;
        acc_cor = fmaf(cor_w * sw, corfeat, acc_cor);
        cws_acc += cor_w;
        sumw_acc += sw;
        nval_acc += valid;
    }

    // finalize: logits = sum_g cf_final*w_reg (8-lane butterfly)
    const float cf_final = acc_cor / sumw_acc / cws_acc;
    float part = cf_final * wreg_g;
    part += __shfl_xor(part, 1);
    part += __shfl_xor(part, 2);
    part += __shfl_xor(part, 4);

    const unsigned int* wsu = (const unsigned int*)wsf;
    const float hmin = __uint_as_float(wsu[0]);
    const float hmax = __uint_as_float(wsu[1]);
    const float logit = part + (depth_d - hmin) / (hmax - hmin);

    if (g == 0) { s_sd[d] = logit; s_val[d] = nval_acc; }
    __syncthreads();

    if (t < 32) {
        const float L = s_sd[t];
        float m = L;
        for (int off = 1; off < 32; off <<= 1) m = fmaxf(m, __shfl_xor(m, off));
        const float e = __expf(L - m);
        float se = e;
        for (int off = 1; off < 32; off <<= 1) se += __shfl_xor(se, off);
        float rse = __builtin_amdgcn_rcpf(se);
        rse = rse * (2.f - se * rse);
        const float attn = e * rse;

        out[OFF_ATTN + t*HWc + pix] = attn;
        out[OFF_NVAL + t*HWc + pix] = s_val[t];

        float av = attn; int ai = t;
        for (int off = 1; off < 32; off <<= 1) {
            float av2 = __shfl_xor(av, off);
            int ai2 = __shfl_xor(ai, off);
            if (av2 > av || (av2 == av && ai2 < ai)) { av = av2; ai = ai2; }
        }
        const float dep = depT[(size_t)pix*Dc + t];
        const float dep_sel = __shfl(dep, ai);
        const float dep0 = __shfl(dep, 0);
        const float dep1 = __shfl(dep, 1);
        if (t == 0) {
            const float last_itv = dep1 - dep0;
            out[OFF_DEPTH + pix] = dep_sel;
            out[OFF_CONF + pix] = av;
            out[OFF_SW + pix] = sumw_acc * 0.25f;
            out[OFF_MIN + pix] = dep_sel - last_itv;
            out[OFF_MAX + pix] = dep_sel + last_itv;
        }
    }
    if (t < 3) {
        float v = np0*w_norm[t*3+0] + np1*w_norm[t*3+1] + np2*w_norm[t*3+2];
        out[OFF_EST + t*HWc + pix] = v;
    }
}

// ---------------- fallback path (original, untransposed) ----------------
__global__ __launch_bounds__(256)
void main_kernel(const float* __restrict__ ref_feature,
                 const float* __restrict__ src_features,
                 const float* __restrict__ normal_plane,
                 const float* __restrict__ depth_hypo,
                 const float* __restrict__ w_reg,
                 const float* __restrict__ w_norm,
                 const float* __restrict__ wsf,
                 float* __restrict__ out) {
    const int pix = blockIdx.x;
    const int t = threadIdx.x;
    const int d = t & 31;
    const int g = t >> 5;
    const float fxp = (float)(pix % Wc);
    const float fyp = (float)(pix / Wc);

    __shared__ float s_cf[Gc*Dc];
    __shared__ float s_valid[Dc];

    float refv[4];
#pragma unroll
    for (int j = 0; j < 4; j++) refv[j] = ref_feature[(g*4+j)*HWc + pix];
    const float np0 = normal_plane[0*HWc + pix];
    const float np1 = normal_plane[1*HWc + pix];
    const float np2 = normal_plane[2*HWc + pix];
    const float depth_d = depth_hypo[d*HWc + pix];
    const float wreg_g = w_reg[g];

    float acc_cor = 0.f;
    float cws_acc = 1e-8f;
    float sumw_acc = 1e-8f;
    float nval_acc = 0.f;

    for (int i = 0; i < NSRC; i++) {
        const float* Wv = wsf + 2 + i*15;
        const float r00=Wv[0], r01=Wv[1], r02=Wv[2];
        const float r10=Wv[3], r11=Wv[4], r12=Wv[5];
        const float r20=Wv[6], r21=Wv[7], r22=Wv[8];
        const float t0=Wv[9], t1=Wv[10], t2=Wv[11];
        const float nv0=Wv[12], nv1=Wv[13], nv2=Wv[14];

        const float b0 = r00*fxp + r01*fyp + r02;
        const float b1 = r10*fxp + r11*fyp + r12;
        const float b2 = r20*fxp + r21*fyp + r22;

        float z = b2*depth_d + t2;
        if (z == 0.f) z = 1e-9f;
        const float px = (b0*depth_d + t0) / z;
        const float py = (b1*depth_d + t1) / z;

        const float fx0 = floorf(px), fy0 = floorf(py);
        const float wx = px - fx0, wy = py - fy0;
        const float fx1 = fx0 + 1.f, fy1 = fy0 + 1.f;
        const bool ix0 = (fx0 >= 0.f) && (fx0 <= (float)(Wc-1));
        const bool ix1 = (fx1 >= 0.f) && (fx1 <= (float)(Wc-1));
        const bool iy0 = (fy0 >= 0.f) && (fy0 <= (float)(Hc-1));
        const bool iy1 = (fy1 >= 0.f) && (fy1 <= (float)(Hc-1));
        const float w00 = (1.f-wx)*(1.f-wy) * ((ix0 && iy0) ? 1.f : 0.f);
        const float w10 = wx*(1.f-wy)       * ((ix1 && iy0) ? 1.f : 0.f);
        const float w01 = (1.f-wx)*wy       * ((ix0 && iy1) ? 1.f : 0.f);
        const float w11 = wx*wy             * ((ix1 && iy1) ? 1.f : 0.f);
        const int xi0 = (int)fminf(fmaxf(fx0, 0.f), (float)(Wc-1));
        const int xi1 = (int)fminf(fmaxf(fx1, 0.f), (float)(Wc-1));
        const int yi0 = (int)fminf(fmaxf(fy0, 0.f), (float)(Hc-1));
        const int yi1 = (int)fminf(fmaxf(fy1, 0.f), (float)(Hc-1));
        const int o00 = yi0*Wc + xi0, o10 = yi0*Wc + xi1;
        const int o01 = yi1*Wc + xi0, o11 = yi1*Wc + xi1;

        const float* src = src_features + (size_t)i * Cc * HWc;
        float corfeat = 0.f;
        float warp0 = 0.f;
#pragma unroll
        for (int j = 0; j < 4; j++) {
            const float* sc = src + (g*4 + j) * HWc;
            float v = w00*sc[o00] + w10*sc[o10] + w01*sc[o01] + w11*sc[o11];
            if (j == 0) warp0 = v;
            corfeat += v * refv[j];
        }
        corfeat *= 0.25f;

        s_cf[t] = corfeat;
        if (g == 0) s_valid[d] = (warp0 != 0.f) ? 1.f : 0.f;
        __syncthreads();

        float s_d = 0.f;
#pragma unroll
        for (int gg = 0; gg < Gc; gg++) s_d += s_cf[gg*32 + d];
        float m = s_d;
        for (int off = 1; off < 32; off <<= 1) m = fmaxf(m, __shfl_xor(m, off));
        float e = expf(s_d - m);
        float se = e;
        for (int off = 1; off < 32; off <<= 1) se += __shfl_xor(se, off);
        const float cor_w = (e / se) * 0.17677669529663687f;

        const float valid = s_valid[d];
        const float src_w = fmaxf(np0*nv0 + np1*nv1 + np2*nv2, 0.f) + 0.01f;
        const float sw = src_w * valid;

        acc_cor += cor_w * sw * corfeat;
        cws_acc += cor_w;
        sumw_acc += sw;
        nval_acc += valid;

        float ssum = sw;
        for (int off = 1; off < 32; off <<= 1) ssum += __shfl_xor(ssum, off);
        if (t == 0) out[OFF_WEIGHT + i*HWc + pix] = ssum * (1.f/32.f);
        __syncthreads();
    }

    const float cf_final = acc_cor / sumw_acc / cws_acc;
    s_cf[t] = cf_final * wreg_g;
    __syncthreads();
    float logit = 0.f;
#pragma unroll
    for (int gg = 0; gg < Gc; gg++) logit += s_cf[gg*32 + d];

    const unsigned int* wsu = (const unsigned int*)wsf;
    const float hmin = __uint_as_float(wsu[0]);
    const float hmax = __uint_as_float(wsu[1]);
    logit += (depth_d - hmin) / (hmax - hmin);

    float m = logit;
    for (int off = 1; off < 32; off <<= 1) m = fmaxf(m, __shfl_xor(m, off));
    float e = expf(logit - m);
    float se = e;
    for (int off = 1; off < 32; off <<= 1) se += __shfl_xor(se, off);
    const float attn = e / se;

    float av = attn; int ai = d;
    for (int off = 1; off < 32; off <<= 1) {
        float av2 = __shfl_xor(av, off);
        int ai2 = __shfl_xor(ai, off);
        if (av2 > av || (av2 == av && ai2 < ai)) { av = av2; ai = ai2; }
    }
    const float dep_sel = __shfl(depth_d, ai, 32);
    const float dep0 = __shfl(depth_d, 0, 32);
    const float dep1 = __shfl(depth_d, 1, 32);
    const float last_itv = dep1 - dep0;

    if (t < 32) {
        out[OFF_ATTN + d*HWc + pix] = attn;
        out[OFF_NVAL + d*HWc + pix] = nval_acc;
    }
    if (t == 0) {
        out[OFF_DEPTH + pix] = dep_sel;
        out[OFF_CONF + pix] = av;
        out[OFF_SW + pix] = sumw_acc * 0.25f;
        out[OFF_MIN + pix] = dep_sel - last_itv;
        out[OFF_MAX + pix] = dep_sel + last_itv;
    }
    if (t < 3) {
        float v = np0*w_norm[t*3+0] + np1*w_norm[t*3+1] + np2*w_norm[t*3+2];
        out[OFF_EST + t*HWc + pix] = v;
    }
}

extern "C" void kernel_launch(void* const* d_in, const int* in_sizes, int n_in,
                              void* d_out, int out_size, void* d_ws, size_t ws_size,
                              hipStream_t stream) {
    const float* ref   = (const float*)d_in[0];
    const float* src   = (const float*)d_in[1];
    const float* rot   = (const float*)d_in[2];
    const float* np_   = (const float*)d_in[3];
    const float* proj  = (const float*)d_in[4];
    const float* dh    = (const float*)d_in[5];
    const float* wreg  = (const float*)d_in[6];
    const float* wnorm = (const float*)d_in[7];
    float* out = (float*)d_out;
    float* ws  = (float*)d_ws;

    setup_kernel<<<1, 1, 0, stream>>>(rot, proj, ws);
    minmax_kernel<<<64, 256, 0, stream>>>(dh, (unsigned int*)ws);

    const size_t need = (size_t)(T_OFF + (size_t)6*Cc*HWc) * sizeof(float);
    if (ws_size >= need) {
        dim3 tg(HWc/64, 6);
        transpose_kernel<<<tg, 256, 0, stream>>>(ref, src, dh, ws + T_OFF);
        main_kernel_t<<<HWc, 256, 0, stream>>>(np_, wreg, wnorm, ws, out);
    } else {
        main_kernel<<<HWc, 256, 0, stream>>>(ref, src, np_, dh, wreg, wnorm, ws, out);
    }
}

// Round 3
// 238.125 us; speedup vs baseline: 1.0414x; 1.0414x over previous
//
#include <hip/hip_runtime.h>
#include <math.h>

#define Vc 5
#define Cc 32
#define Gc 8
#define Dc 32
#define Hc 192
#define Wc 192
#define HWc (Hc*Wc)
#define NSRC (Vc-1)

// output offsets (floats)
#define OFF_DEPTH  0
#define OFF_CONF   (HWc)
#define OFF_ATTN   (2*HWc)
#define OFF_EST    (OFF_ATTN + Dc*HWc)
#define OFF_SW     (OFF_EST + 3*HWc)
#define OFF_WEIGHT (OFF_SW + HWc)
#define OFF_NVAL   (OFF_WEIGHT + NSRC*HWc)
#define OFF_MIN    (OFF_NVAL + Dc*HWc)
#define OFF_MAX    (OFF_MIN + HWc)

// ws layout (floats):
//   [0]=hmin bits(uint) [1]=hmax bits(uint)   (init by hipMemsetAsync)
//   [2 + i*15]: rot(9), trans(3), norv(3)
//   [64 + k*Cc*HWc]: channels-last src views k=0..3 ([HW][C] each)
#define T_OFF 64

__device__ void inv4(const float* A, float* out) {
    float M[4][8];
    for (int r = 0; r < 4; r++) {
        for (int c = 0; c < 4; c++) { M[r][c] = A[r*4+c]; M[r][c+4] = (r == c) ? 1.f : 0.f; }
    }
    for (int col = 0; col < 4; col++) {
        int piv = col; float best = fabsf(M[col][col]);
        for (int r = col+1; r < 4; r++) { float v = fabsf(M[r][col]); if (v > best) { best = v; piv = r; } }
        if (piv != col) for (int c = 0; c < 8; c++) { float t = M[col][c]; M[col][c] = M[piv][c]; M[piv][c] = t; }
        float inv = 1.f / M[col][col];
        for (int c = 0; c < 8; c++) M[col][c] *= inv;
        for (int r = 0; r < 4; r++) {
            if (r == col) continue;
            float f = M[r][col];
            for (int c = 0; c < 8; c++) M[r][c] -= f * M[col][c];
        }
    }
    for (int r = 0; r < 4; r++) for (int c = 0; c < 4; c++) out[r*4+c] = M[r][c+4];
}

__device__ void inv3(const float* A, float* out) {
    float a=A[0],b=A[1],c=A[2],d=A[3],e=A[4],f=A[5],g=A[6],h=A[7],i=A[8];
    float det = a*(e*i-f*h) - b*(d*i-f*g) + c*(d*h-e*g);
    float id = 1.f/det;
    out[0]=(e*i-f*h)*id; out[1]=(c*h-b*i)*id; out[2]=(b*f-c*e)*id;
    out[3]=(f*g-d*i)*id; out[4]=(a*i-c*g)*id; out[5]=(c*d-a*f)*id;
    out[6]=(d*h-e*g)*id; out[7]=(b*g-a*h)*id; out[8]=(a*e-b*d)*id;
}

__device__ void setup_body(const float* __restrict__ rotation,
                           const float* __restrict__ proj,
                           float* __restrict__ wsf) {
    float refE[16], refK[16], refNew[16], invRef[16];
    for (int k = 0; k < 16; k++) { refE[k] = proj[k]; refK[k] = proj[16+k]; }
    for (int k = 0; k < 16; k++) refNew[k] = refE[k];
    for (int r = 0; r < 3; r++) for (int c = 0; c < 4; c++) {
        float s = 0.f;
        for (int k = 0; k < 3; k++) s += refK[r*4+k] * refE[k*4+c];
        refNew[r*4+c] = s;
    }
    inv4(refNew, invRef);
    float invR0[9];
    inv3(rotation, invR0);

    for (int i = 0; i < NSRC; i++) {
        const float* E = proj + (i+1)*32;
        const float* K = proj + (i+1)*32 + 16;
        float sNew[16];
        for (int k = 0; k < 16; k++) sNew[k] = E[k];
        for (int r = 0; r < 3; r++) for (int c = 0; c < 4; c++) {
            float s = 0.f;
            for (int k = 0; k < 3; k++) s += K[r*4+k] * E[k*4+c];
            sNew[r*4+c] = s;
        }
        float P[16];
        for (int r = 0; r < 4; r++) for (int c = 0; c < 4; c++) {
            float s = 0.f;
            for (int k = 0; k < 4; k++) s += sNew[r*4+k] * invRef[k*4+c];
            P[r*4+c] = s;
        }
        float* o = wsf + 2 + i*15;
        for (int r = 0; r < 3; r++) for (int c = 0; c < 3; c++) o[r*3+c] = P[r*4+c];
        for (int r = 0; r < 3; r++) o[9+r] = P[r*4+3];
        const float* Ri = rotation + (i+1)*9;
        for (int c = 0; c < 3; c++) {
            float s = 0.f;
            for (int k = 0; k < 3; k++) s += Ri[2*3+k] * invR0[k*3+c];
            o[12+c] = s;
        }
    }
}

// Fused: grid-stride depth min/max (64 blocks; ws[0..1] init'd by memsets)
// + matrix setup on block 0 thread 0 (tail work, hidden under other blocks).
__global__ __launch_bounds__(256)
void setup_minmax_kernel(const float* __restrict__ rotation,
                         const float* __restrict__ proj,
                         const float* __restrict__ depth,
                         float* __restrict__ wsf) {
    unsigned int* wsu = (unsigned int*)wsf;
    const int tid = blockIdx.x * blockDim.x + threadIdx.x;
    const int stride = gridDim.x * blockDim.x;
    const int n4 = (Dc*HWc) / 4;
    const float4* d4 = (const float4*)depth;
    float mn = __uint_as_float(0x7F800000u);
    float mx = 0.f;
    for (int idx = tid; idx < n4; idx += stride) {
        float4 v = d4[idx];
        mn = fminf(mn, fminf(fminf(v.x, v.y), fminf(v.z, v.w)));
        mx = fmaxf(mx, fmaxf(fmaxf(v.x, v.y), fmaxf(v.z, v.w)));
    }
    for (int off = 32; off; off >>= 1) {
        mn = fminf(mn, __shfl_xor(mn, off));
        mx = fmaxf(mx, __shfl_xor(mx, off));
    }
    __shared__ float smn[4], smx[4];
    const int w = threadIdx.x >> 6;
    if ((threadIdx.x & 63) == 0) { smn[w] = mn; smx[w] = mx; }
    __syncthreads();
    if (threadIdx.x == 0) {
        for (int i = 1; i < 4; i++) { mn = fminf(mn, smn[i]); mx = fmaxf(mx, smx[i]); }
        atomicMin(&wsu[0], __float_as_uint(mn));
        atomicMax(&wsu[1], __float_as_uint(mx));
    }
    if (blockIdx.x == 0 && threadIdx.x == 0)
        setup_body(rotation, proj, wsf);
}

// [C][HW] -> [HW][C] channels-last transpose, src views only (ref/depth are
// read block-uniformly in main and don't need the layout change).
__global__ __launch_bounds__(256)
void transpose_kernel(const float* __restrict__ src,
                      float* __restrict__ wsT) {
    const int img = blockIdx.y;          // 0..3
    const int p0  = blockIdx.x * 64;
    const float* in = src + (size_t)img*Cc*HWc;
    float* outp = wsT + (size_t)img * Cc * HWc;
    __shared__ float tile[Cc][64+1];
    const int t = threadIdx.x;
#pragma unroll
    for (int k = 0; k < 8; k++) {
        const int c = (t >> 6) + k*4;
        const int p = t & 63;
        tile[c][p] = in[(size_t)c*HWc + p0 + p];
    }
    __syncthreads();
#pragma unroll
    for (int k = 0; k < 8; k++) {
        const int c = t & 31;
        const int p = (t >> 5) + k*8;
        outp[(size_t)(p0 + p)*Cc + c] = tile[c][p];
    }
}

// Bilinear weight + pre-scaled tap-offset computation for one (pix, d, view).
__device__ __forceinline__ void compute_wo(float fxp, float fyp, const float* __restrict__ Wv,
                                           float dep, float4* wout, int4* oout) {
    const float b0 = Wv[0]*fxp + Wv[1]*fyp + Wv[2];
    const float b1 = Wv[3]*fxp + Wv[4]*fyp + Wv[5];
    const float b2 = Wv[6]*fxp + Wv[7]*fyp + Wv[8];
    float z = fmaf(b2, dep, Wv[11]);
    if (z == 0.f) z = 1e-9f;
    float rz = __builtin_amdgcn_rcpf(z);
    rz = rz * (2.f - z * rz);                 // Newton refine
    const float px = fmaf(b0, dep, Wv[9])  * rz;
    const float py = fmaf(b1, dep, Wv[10]) * rz;

    const float fx0 = floorf(px), fy0 = floorf(py);
    const float wx = px - fx0, wy = py - fy0;
    const float fx1 = fx0 + 1.f, fy1 = fy0 + 1.f;
    const bool ix0 = (fx0 >= 0.f) && (fx0 <= (float)(Wc-1));
    const bool ix1 = (fx1 >= 0.f) && (fx1 <= (float)(Wc-1));
    const bool iy0 = (fy0 >= 0.f) && (fy0 <= (float)(Hc-1));
    const bool iy1 = (fy1 >= 0.f) && (fy1 <= (float)(Hc-1));
    const float w00 = (1.f-wx)*(1.f-wy) * ((ix0 && iy0) ? 1.f : 0.f);
    const float w10 = wx*(1.f-wy)       * ((ix1 && iy0) ? 1.f : 0.f);
    const float w01 = (1.f-wx)*wy       * ((ix0 && iy1) ? 1.f : 0.f);
    const float w11 = wx*wy             * ((ix1 && iy1) ? 1.f : 0.f);
    const int xi0 = (int)fminf(fmaxf(fx0, 0.f), (float)(Wc-1));
    const int xi1 = (int)fminf(fmaxf(fx1, 0.f), (float)(Wc-1));
    const int yi0 = (int)fminf(fmaxf(fy0, 0.f), (float)(Hc-1));
    const int yi1 = (int)fminf(fmaxf(fy1, 0.f), (float)(Hc-1));
    *wout = make_float4(w00, w10, w01, w11);
    *oout = make_int4((yi0*Wc + xi0)*8, (yi0*Wc + xi1)*8,
                      (yi1*Wc + xi0)*8, (yi1*Wc + xi1)*8);   // float4 units
}

// Restructured main kernel: all wave-parallel phases, 4 barriers total.
//   phase 1: wave w computes view w's 32 weight/offset records (parallel)
//   phase 2: barrier-free 16-gather stream (4 views x 4 taps, full ILP)
//   phase 3: wave w does view w's d-softmax + sims (parallel)
//   phase 4: accumulate from registers
__global__ __launch_bounds__(256)
void main_kernel_t(const float* __restrict__ ref_feature,
                   const float* __restrict__ normal_plane,
                   const float* __restrict__ depth_hypo,
                   const float* __restrict__ w_reg,
                   const float* __restrict__ w_norm,
                   const float* __restrict__ wsf,
                   float* __restrict__ out) {
    // bijective XCD swizzle: consecutive pix co-resident per XCD -> output
    // lines + gather lines merge in that XCD's L2 (R2: WRITE_SIZE 87.5->10.9MB)
    const int bid = blockIdx.x;
    const int pix = (bid & 7) * (HWc/8) + (bid >> 3);
    const int t = threadIdx.x;
    const int g = t & 7;
    const int d = t >> 3;
    const int lane = t & 63;
    const int wv_id = t >> 6;     // wave index == view index
    const int wl = t & 63;
    const float fxp = (float)(pix % Wc);
    const float fyp = (float)(pix / Wc);

    const float4* srcT0 = (const float4*)(wsf + T_OFF);

    __shared__ float4 s_wt[NSRC][Dc];
    __shared__ int4   s_of[NSRC][Dc];
    __shared__ float  s_sd[NSRC][Dc];
    __shared__ float  s_val[NSRC][Dc];
    __shared__ float  s_w[NSRC][Dc];
    __shared__ float  s_dep[Dc];

    // ref fragment: block-uniform column reads, L2-served; fold mean(C//G)
    float4 rv;
    rv.x = ref_feature[(g*4+0)*HWc + pix] * 0.25f;
    rv.y = ref_feature[(g*4+1)*HWc + pix] * 0.25f;
    rv.z = ref_feature[(g*4+2)*HWc + pix] * 0.25f;
    rv.w = ref_feature[(g*4+3)*HWc + pix] * 0.25f;
    const float np0 = normal_plane[0*HWc + pix];
    const float np1 = normal_plane[1*HWc + pix];
    const float np2 = normal_plane[2*HWc + pix];
    const float depth_d = depth_hypo[d*HWc + pix];
    const float wreg_g = w_reg[g];

    // per-view src weights (uniform over threads; static-indexed in unrolled loops)
    float srcw[NSRC];
#pragma unroll
    for (int i = 0; i < NSRC; i++) {
        const float* Wv = wsf + 2 + i*15;
        srcw[i] = fmaxf(np0*Wv[12] + np1*Wv[13] + np2*Wv[14], 0.f) + 0.01f;
    }

    // ---- phase 1: parallel weight compute (wave w -> view w) ----
    if (wl < 32)
        compute_wo(fxp, fyp, wsf + 2 + wv_id*15, depth_hypo[wl*HWc + pix],
                   &s_wt[wv_id][wl], &s_of[wv_id][wl]);
    if (g == 0) s_dep[d] = depth_d;
    __syncthreads();

    // ---- phase 2: barrier-free gather + blend stream over all views ----
    float corfeat[NSRC], validv[NSRC];
#pragma unroll
    for (int i = 0; i < NSRC; i++) {
        const float4 wv = s_wt[i][d];
        const int4   ov = s_of[i][d];
        const float4* sp = srcT0 + (size_t)i*HWc*8 + g;
        const float4 v00 = sp[ov.x];
        const float4 v10 = sp[ov.y];
        const float4 v01 = sp[ov.z];
        const float4 v11 = sp[ov.w];
        const float bx = wv.x*v00.x + wv.y*v10.x + wv.z*v01.x + wv.w*v11.x;
        const float by = wv.x*v00.y + wv.y*v10.y + wv.z*v01.y + wv.w*v11.y;
        const float bz = wv.x*v00.z + wv.y*v10.z + wv.z*v01.z + wv.w*v11.z;
        const float bw = wv.x*v00.w + wv.y*v10.w + wv.z*v01.w + wv.w*v11.w;
        corfeat[i] = bx*rv.x + by*rv.y + bz*rv.z + bw*rv.w;

        float sd = corfeat[i];
        sd += __shfl_xor(sd, 1);
        sd += __shfl_xor(sd, 2);
        sd += __shfl_xor(sd, 4);

        const float c0 = __shfl(bx, lane & ~7);   // g==0 lane's channel-0 blend
        validv[i] = (c0 != 0.f) ? 1.f : 0.f;

        if (g == 0) { s_sd[i][d] = sd; s_val[i][d] = validv[i]; }
    }
    __syncthreads();

    // ---- phase 3: parallel softmax (wave w -> view w) + sims ----
    if (wl < 32) {
        const float u = s_sd[wv_id][wl];
        float m = u;
        for (int off = 1; off < 32; off <<= 1) m = fmaxf(m, __shfl_xor(m, off));
        const float e = __expf(u - m);
        float se = e;
        for (int off = 1; off < 32; off <<= 1) se += __shfl_xor(se, off);
        float rse = __builtin_amdgcn_rcpf(se);
        rse = rse * (2.f - se * rse);
        s_w[wv_id][wl] = e * rse * 0.17677669529663687f;  // softmax / sqrt(C)

        const float* Wv = wsf + 2 + wv_id*15;
        const float srcw_w = fmaxf(np0*Wv[12] + np1*Wv[13] + np2*Wv[14], 0.f) + 0.01f;
        float ss = srcw_w * s_val[wv_id][wl];
        for (int off = 1; off < 32; off <<= 1) ss += __shfl_xor(ss, off);
        if (wl == 0) out[OFF_WEIGHT + wv_id*HWc + pix] = ss * (1.f/32.f);
    }
    __syncthreads();

    // ---- phase 4: accumulate (all threads, registers + LDS broadcast) ----
    float acc_cor = 0.f;
    float cws_acc = 1e-8f;
    float sumw_acc = 1e-8f;
    float nval_acc = 0.f;
#pragma unroll
    for (int i = 0; i < NSRC; i++) {
        const float cor_w = s_w[i][d];
        const float sw = srcw[i] * validv[i];
        acc_cor = fmaf(cor_w * sw, corfeat[i], acc_cor);
        cws_acc += cor_w;
        sumw_acc += sw;
        nval_acc += validv[i];
    }

    // finalize: logits = sum_g cf_final*w_reg (8-lane butterfly)
    const float cf_final = acc_cor / sumw_acc / cws_acc;
    float part = cf_final * wreg_g;
    part += __shfl_xor(part, 1);
    part += __shfl_xor(part, 2);
    part += __shfl_xor(part, 4);

    const unsigned int* wsu = (const unsigned int*)wsf;
    const float hmin = __uint_as_float(wsu[0]);
    const float hmax = __uint_as_float(wsu[1]);
    const float logit = part + (depth_d - hmin) / (hmax - hmin);

    if (g == 0) { s_sd[0][d] = logit; s_val[0][d] = nval_acc; }
    __syncthreads();

    if (t < 32) {
        const float L = s_sd[0][t];
        float m = L;
        for (int off = 1; off < 32; off <<= 1) m = fmaxf(m, __shfl_xor(m, off));
        const float e = __expf(L - m);
        float se = e;
        for (int off = 1; off < 32; off <<= 1) se += __shfl_xor(se, off);
        float rse = __builtin_amdgcn_rcpf(se);
        rse = rse * (2.f - se * rse);
        const float attn = e * rse;

        out[OFF_ATTN + t*HWc + pix] = attn;
        out[OFF_NVAL + t*HWc + pix] = s_val[0][t];

        float av = attn; int ai = t;
        for (int off = 1; off < 32; off <<= 1) {
            float av2 = __shfl_xor(av, off);
            int ai2 = __shfl_xor(ai, off);
            if (av2 > av || (av2 == av && ai2 < ai)) { av = av2; ai = ai2; }
        }
        const float dep = s_dep[t];
        const float dep_sel = __shfl(dep, ai);
        const float dep0 = __shfl(dep, 0);
        const float dep1 = __shfl(dep, 1);
        if (t == 0) {
            const float last_itv = dep1 - dep0;
            out[OFF_DEPTH + pix] = dep_sel;
            out[OFF_CONF + pix] = av;
            out[OFF_SW + pix] = sumw_acc * 0.25f;   // d==0 lane, /nsrc
            out[OFF_MIN + pix] = dep_sel - last_itv;
            out[OFF_MAX + pix] = dep_sel + last_itv;
        }
    }
    if (t < 3) {
        float v = np0*w_norm[t*3+0] + np1*w_norm[t*3+1] + np2*w_norm[t*3+2];
        out[OFF_EST + t*HWc + pix] = v;
    }
}

// ---------------- fallback path (original, untransposed) ----------------
__global__ __launch_bounds__(256)
void main_kernel(const float* __restrict__ ref_feature,
                 const float* __restrict__ src_features,
                 const float* __restrict__ normal_plane,
                 const float* __restrict__ depth_hypo,
                 const float* __restrict__ w_reg,
                 const float* __restrict__ w_norm,
                 const float* __restrict__ wsf,
                 float* __restrict__ out) {
    const int pix = blockIdx.x;
    const int t = threadIdx.x;
    const int d = t & 31;
    const int g = t >> 5;
    const float fxp = (float)(pix % Wc);
    const float fyp = (float)(pix / Wc);

    __shared__ float s_cf[Gc*Dc];
    __shared__ float s_valid[Dc];

    float refv[4];
#pragma unroll
    for (int j = 0; j < 4; j++) refv[j] = ref_feature[(g*4+j)*HWc + pix];
    const float np0 = normal_plane[0*HWc + pix];
    const float np1 = normal_plane[1*HWc + pix];
    const float np2 = normal_plane[2*HWc + pix];
    const float depth_d = depth_hypo[d*HWc + pix];
    const float wreg_g = w_reg[g];

    float acc_cor = 0.f;
    float cws_acc = 1e-8f;
    float sumw_acc = 1e-8f;
    float nval_acc = 0.f;

    for (int i = 0; i < NSRC; i++) {
        const float* Wv = wsf + 2 + i*15;
        const float r00=Wv[0], r01=Wv[1], r02=Wv[2];
        const float r10=Wv[3], r11=Wv[4], r12=Wv[5];
        const float r20=Wv[6], r21=Wv[7], r22=Wv[8];
        const float t0=Wv[9], t1=Wv[10], t2=Wv[11];
        const float nv0=Wv[12], nv1=Wv[13], nv2=Wv[14];

        const float b0 = r00*fxp + r01*fyp + r02;
        const float b1 = r10*fxp + r11*fyp + r12;
        const float b2 = r20*fxp + r21*fyp + r22;

        float z = b2*depth_d + t2;
        if (z == 0.f) z = 1e-9f;
        const float px = (b0*depth_d + t0) / z;
        const float py = (b1*depth_d + t1) / z;

        const float fx0 = floorf(px), fy0 = floorf(py);
        const float wx = px - fx0, wy = py - fy0;
        const float fx1 = fx0 + 1.f, fy1 = fy0 + 1.f;
        const bool ix0 = (fx0 >= 0.f) && (fx0 <= (float)(Wc-1));
        const bool ix1 = (fx1 >= 0.f) && (fx1 <= (float)(Wc-1));
        const bool iy0 = (fy0 >= 0.f) && (fy0 <= (float)(Hc-1));
        const bool iy1 = (fy1 >= 0.f) && (fy1 <= (float)(Hc-1));
        const float w00 = (1.f-wx)*(1.f-wy) * ((ix0 && iy0) ? 1.f : 0.f);
        const float w10 = wx*(1.f-wy)       * ((ix1 && iy0) ? 1.f : 0.f);
        const float w01 = (1.f-wx)*wy       * ((ix0 && iy1) ? 1.f : 0.f);
        const float w11 = wx*wy             * ((ix1 && iy1) ? 1.f : 0.f);
        const int xi0 = (int)fminf(fmaxf(fx0, 0.f), (float)(Wc-1));
        const int xi1 = (int)fminf(fmaxf(fx1, 0.f), (float)(Wc-1));
        const int yi0 = (int)fminf(fmaxf(fy0, 0.f), (float)(Hc-1));
        const int yi1 = (int)fminf(fmaxf(fy1, 0.f), (float)(Hc-1));
        const int o00 = yi0*Wc + xi0, o10 = yi0*Wc + xi1;
        const int o01 = yi1*Wc + xi0, o11 = yi1*Wc + xi1;

        const float* src = src_features + (size_t)i * Cc * HWc;
        float corfeat = 0.f;
        float warp0 = 0.f;
#pragma unroll
        for (int j = 0; j < 4; j++) {
            const float* sc = src + (g*4 + j) * HWc;
            float v = w00*sc[o00] + w10*sc[o10] + w01*sc[o01] + w11*sc[o11];
            if (j == 0) warp0 = v;
            corfeat += v * refv[j];
        }
        corfeat *= 0.25f;

        s_cf[t] = corfeat;
        if (g == 0) s_valid[d] = (warp0 != 0.f) ? 1.f : 0.f;
        __syncthreads();

        float s_d = 0.f;
#pragma unroll
        for (int gg = 0; gg < Gc; gg++) s_d += s_cf[gg*32 + d];
        float m = s_d;
        for (int off = 1; off < 32; off <<= 1) m = fmaxf(m, __shfl_xor(m, off));
        float e = expf(s_d - m);
        float se = e;
        for (int off = 1; off < 32; off <<= 1) se += __shfl_xor(se, off);
        const float cor_w = (e / se) * 0.17677669529663687f;

        const float valid = s_valid[d];
        const float src_w = fmaxf(np0*nv0 + np1*nv1 + np2*nv2, 0.f) + 0.01f;
        const float sw = src_w * valid;

        acc_cor += cor_w * sw * corfeat;
        cws_acc += cor_w;
        sumw_acc += sw;
        nval_acc += valid;

        float ssum = sw;
        for (int off = 1; off < 32; off <<= 1) ssum += __shfl_xor(ssum, off);
        if (t == 0) out[OFF_WEIGHT + i*HWc + pix] = ssum * (1.f/32.f);
        __syncthreads();
    }

    const float cf_final = acc_cor / sumw_acc / cws_acc;
    s_cf[t] = cf_final * wreg_g;
    __syncthreads();
    float logit = 0.f;
#pragma unroll
    for (int gg = 0; gg < Gc; gg++) logit += s_cf[gg*32 + d];

    const unsigned int* wsu = (const unsigned int*)wsf;
    const float hmin = __uint_as_float(wsu[0]);
    const float hmax = __uint_as_float(wsu[1]);
    logit += (depth_d - hmin) / (hmax - hmin);

    float m = logit;
    for (int off = 1; off < 32; off <<= 1) m = fmaxf(m, __shfl_xor(m, off));
    float e = expf(logit - m);
    float se = e;
    for (int off = 1; off < 32; off <<= 1) se += __shfl_xor(se, off);
    const float attn = e / se;

    float av = attn; int ai = d;
    for (int off = 1; off < 32; off <<= 1) {
        float av2 = __shfl_xor(av, off);
        int ai2 = __shfl_xor(ai, off);
        if (av2 > av || (av2 == av && ai2 < ai)) { av = av2; ai = ai2; }
    }
    const float dep_sel = __shfl(depth_d, ai, 32);
    const float dep0 = __shfl(depth_d, 0, 32);
    const float dep1 = __shfl(depth_d, 1, 32);
    const float last_itv = dep1 - dep0;

    if (t < 32) {
        out[OFF_ATTN + d*HWc + pix] = attn;
        out[OFF_NVAL + d*HWc + pix] = nval_acc;
    }
    if (t == 0) {
        out[OFF_DEPTH + pix] = dep_sel;
        out[OFF_CONF + pix] = av;
        out[OFF_SW + pix] = sumw_acc * 0.25f;
        out[OFF_MIN + pix] = dep_sel - last_itv;
        out[OFF_MAX + pix] = dep_sel + last_itv;
    }
    if (t < 3) {
        float v = np0*w_norm[t*3+0] + np1*w_norm[t*3+1] + np2*w_norm[t*3+2];
        out[OFF_EST + t*HWc + pix] = v;
    }
}

extern "C" void kernel_launch(void* const* d_in, const int* in_sizes, int n_in,
                              void* d_out, int out_size, void* d_ws, size_t ws_size,
                              hipStream_t stream) {
    const float* ref   = (const float*)d_in[0];
    const float* src   = (const float*)d_in[1];
    const float* rot   = (const float*)d_in[2];
    const float* np_   = (const float*)d_in[3];
    const float* proj  = (const float*)d_in[4];
    const float* dh    = (const float*)d_in[5];
    const float* wreg  = (const float*)d_in[6];
    const float* wnorm = (const float*)d_in[7];
    float* out = (float*)d_out;
    float* ws  = (float*)d_ws;

    // init hmin (uint-min: 0xFFFFFFFF) / hmax (0) for the fused atomics
    hipMemsetAsync((char*)d_ws + 0, 0xFF, 4, stream);
    hipMemsetAsync((char*)d_ws + 4, 0x00, 4, stream);
    setup_minmax_kernel<<<64, 256, 0, stream>>>(rot, proj, dh, ws);

    const size_t need = (size_t)(T_OFF + (size_t)NSRC*Cc*HWc) * sizeof(float);
    if (ws_size >= need) {
        dim3 tg(HWc/64, NSRC);
        transpose_kernel<<<tg, 256, 0, stream>>>(src, ws + T_OFF);
        main_kernel_t<<<HWc, 256, 0, stream>>>(ref, np_, dh, wreg, wnorm, ws, out);
    } else {
        main_kernel<<<HWc, 256, 0, stream>>>(ref, src, np_, dh, wreg, wnorm, ws, out);
    }
}

// Round 4
// 214.096 us; speedup vs baseline: 1.1583x; 1.1122x over previous
//
#include <hip/hip_runtime.h>
#include <math.h>

#define Vc 5
#define Cc 32
#define Gc 8
#define Dc 32
#define Hc 192
#define Wc 192
#define HWc (Hc*Wc)
#define NSRC (Vc-1)

// output offsets (floats)
#define OFF_DEPTH  0
#define OFF_CONF   (HWc)
#define OFF_ATTN   (2*HWc)
#define OFF_EST    (OFF_ATTN + Dc*HWc)
#define OFF_SW     (OFF_EST + 3*HWc)
#define OFF_WEIGHT (OFF_SW + HWc)
#define OFF_NVAL   (OFF_WEIGHT + NSRC*HWc)
#define OFF_MIN    (OFF_NVAL + Dc*HWc)
#define OFF_MAX    (OFF_MIN + HWc)

// ws layout (floats):
//   [0]=hmin bits(uint) [1]=hmax bits(uint)   (init by hipMemsetAsync)
//   [2 + i*15]: rot(9), trans(3), norv(3)
//   [64]: channels-last images, img=0..3 src views, img=4 ref, img=5 depth
//         ([HW][32] each). Needs ws >= 28.4 MB; host falls back otherwise.
#define T_OFF 64

__device__ void inv4(const float* A, float* out) {
    float M[4][8];
    for (int r = 0; r < 4; r++) {
        for (int c = 0; c < 4; c++) { M[r][c] = A[r*4+c]; M[r][c+4] = (r == c) ? 1.f : 0.f; }
    }
    for (int col = 0; col < 4; col++) {
        int piv = col; float best = fabsf(M[col][col]);
        for (int r = col+1; r < 4; r++) { float v = fabsf(M[r][col]); if (v > best) { best = v; piv = r; } }
        if (piv != col) for (int c = 0; c < 8; c++) { float t = M[col][c]; M[col][c] = M[piv][c]; M[piv][c] = t; }
        float inv = 1.f / M[col][col];
        for (int c = 0; c < 8; c++) M[col][c] *= inv;
        for (int r = 0; r < 4; r++) {
            if (r == col) continue;
            float f = M[r][col];
            for (int c = 0; c < 8; c++) M[r][c] -= f * M[col][c];
        }
    }
    for (int r = 0; r < 4; r++) for (int c = 0; c < 4; c++) out[r*4+c] = M[r][c+4];
}

__device__ void inv3(const float* A, float* out) {
    float a=A[0],b=A[1],c=A[2],d=A[3],e=A[4],f=A[5],g=A[6],h=A[7],i=A[8];
    float det = a*(e*i-f*h) - b*(d*i-f*g) + c*(d*h-e*g);
    float id = 1.f/det;
    out[0]=(e*i-f*h)*id; out[1]=(c*h-b*i)*id; out[2]=(b*f-c*e)*id;
    out[3]=(f*g-d*i)*id; out[4]=(a*i-c*g)*id; out[5]=(c*d-a*f)*id;
    out[6]=(d*h-e*g)*id; out[7]=(b*g-a*h)*id; out[8]=(a*e-b*d)*id;
}

__device__ void setup_body(const float* __restrict__ rotation,
                           const float* __restrict__ proj,
                           float* __restrict__ wsf) {
    float refE[16], refK[16], refNew[16], invRef[16];
    for (int k = 0; k < 16; k++) { refE[k] = proj[k]; refK[k] = proj[16+k]; }
    for (int k = 0; k < 16; k++) refNew[k] = refE[k];
    for (int r = 0; r < 3; r++) for (int c = 0; c < 4; c++) {
        float s = 0.f;
        for (int k = 0; k < 3; k++) s += refK[r*4+k] * refE[k*4+c];
        refNew[r*4+c] = s;
    }
    inv4(refNew, invRef);
    float invR0[9];
    inv3(rotation, invR0);

    for (int i = 0; i < NSRC; i++) {
        const float* E = proj + (i+1)*32;
        const float* K = proj + (i+1)*32 + 16;
        float sNew[16];
        for (int k = 0; k < 16; k++) sNew[k] = E[k];
        for (int r = 0; r < 3; r++) for (int c = 0; c < 4; c++) {
            float s = 0.f;
            for (int k = 0; k < 3; k++) s += K[r*4+k] * E[k*4+c];
            sNew[r*4+c] = s;
        }
        float P[16];
        for (int r = 0; r < 4; r++) for (int c = 0; c < 4; c++) {
            float s = 0.f;
            for (int k = 0; k < 4; k++) s += sNew[r*4+k] * invRef[k*4+c];
            P[r*4+c] = s;
        }
        float* o = wsf + 2 + i*15;
        for (int r = 0; r < 3; r++) for (int c = 0; c < 3; c++) o[r*3+c] = P[r*4+c];
        for (int r = 0; r < 3; r++) o[9+r] = P[r*4+3];
        const float* Ri = rotation + (i+1)*9;
        for (int c = 0; c < 3; c++) {
            float s = 0.f;
            for (int k = 0; k < 3; k++) s += Ri[2*3+k] * invR0[k*3+c];
            o[12+c] = s;
        }
    }
}

// Fused prep: [C][HW]->[HW][C] transpose of {src x4, ref, depth}; the depth
// blocks (img==5) also reduce their tile's min/max -> 1 atomic pair/block;
// matrix setup rides on block (0,0) thread 0. ws[0..1] init'd by memsets.
__global__ __launch_bounds__(256)
void prep_kernel(const float* __restrict__ src,
                 const float* __restrict__ ref,
                 const float* __restrict__ depth,
                 const float* __restrict__ rotation,
                 const float* __restrict__ proj,
                 float* __restrict__ wsf) {
    const int img = blockIdx.y;          // 0..3 src, 4 ref, 5 depth
    const int p0  = blockIdx.x * 64;
    const float* in = (img < NSRC) ? (src + (size_t)img*Cc*HWc)
                    : (img == NSRC) ? ref : depth;
    float* outp = wsf + T_OFF + (size_t)img * Cc * HWc;
    __shared__ float tile[Cc][64+1];
    const int t = threadIdx.x;
    float mn = __uint_as_float(0x7F800000u);
    float mx = 0.f;
#pragma unroll
    for (int k = 0; k < 8; k++) {
        const int c = (t >> 6) + k*4;
        const int p = t & 63;
        const float v = in[(size_t)c*HWc + p0 + p];
        tile[c][p] = v;
        mn = fminf(mn, v);
        mx = fmaxf(mx, v);
    }
    __syncthreads();
#pragma unroll
    for (int k = 0; k < 8; k++) {
        const int c = t & 31;
        const int p = (t >> 5) + k*8;
        outp[(size_t)(p0 + p)*Cc + c] = tile[c][p];
    }
    if (img == 5) {   // depth tile: global min/max via one atomic pair/block
        for (int off = 32; off; off >>= 1) {
            mn = fminf(mn, __shfl_xor(mn, off));
            mx = fmaxf(mx, __shfl_xor(mx, off));
        }
        __shared__ float smn[4], smx[4];
        const int w = t >> 6;
        if ((t & 63) == 0) { smn[w] = mn; smx[w] = mx; }
        __syncthreads();
        if (t == 0) {
            unsigned int* wsu = (unsigned int*)wsf;
            for (int i = 1; i < 4; i++) { mn = fminf(mn, smn[i]); mx = fmaxf(mx, smx[i]); }
            atomicMin(&wsu[0], __float_as_uint(mn));
            atomicMax(&wsu[1], __float_as_uint(mx));
        }
    }
    if (img == 0 && blockIdx.x == 0 && t == 0)
        setup_body(rotation, proj, wsf);
}

// Bilinear weight + pre-scaled tap-offset computation for one (pix, d, view).
__device__ __forceinline__ void compute_wo(float fxp, float fyp, const float* __restrict__ Wv,
                                           float dep, float4* wout, int4* oout) {
    const float b0 = Wv[0]*fxp + Wv[1]*fyp + Wv[2];
    const float b1 = Wv[3]*fxp + Wv[4]*fyp + Wv[5];
    const float b2 = Wv[6]*fxp + Wv[7]*fyp + Wv[8];
    float z = fmaf(b2, dep, Wv[11]);
    if (z == 0.f) z = 1e-9f;
    float rz = __builtin_amdgcn_rcpf(z);
    rz = rz * (2.f - z * rz);                 // Newton refine
    const float px = fmaf(b0, dep, Wv[9])  * rz;
    const float py = fmaf(b1, dep, Wv[10]) * rz;

    const float fx0 = floorf(px), fy0 = floorf(py);
    const float wx = px - fx0, wy = py - fy0;
    const float fx1 = fx0 + 1.f, fy1 = fy0 + 1.f;
    const bool ix0 = (fx0 >= 0.f) && (fx0 <= (float)(Wc-1));
    const bool ix1 = (fx1 >= 0.f) && (fx1 <= (float)(Wc-1));
    const bool iy0 = (fy0 >= 0.f) && (fy0 <= (float)(Hc-1));
    const bool iy1 = (fy1 >= 0.f) && (fy1 <= (float)(Hc-1));
    const float w00 = (1.f-wx)*(1.f-wy) * ((ix0 && iy0) ? 1.f : 0.f);
    const float w10 = wx*(1.f-wy)       * ((ix1 && iy0) ? 1.f : 0.f);
    const float w01 = (1.f-wx)*wy       * ((ix0 && iy1) ? 1.f : 0.f);
    const float w11 = wx*wy             * ((ix1 && iy1) ? 1.f : 0.f);
    const int xi0 = (int)fminf(fmaxf(fx0, 0.f), (float)(Wc-1));
    const int xi1 = (int)fminf(fmaxf(fx1, 0.f), (float)(Wc-1));
    const int yi0 = (int)fminf(fmaxf(fy0, 0.f), (float)(Hc-1));
    const int yi1 = (int)fminf(fmaxf(fy1, 0.f), (float)(Hc-1));
    *wout = make_float4(w00, w10, w01, w11);
    *oout = make_int4((yi0*Wc + xi0)*8, (yi0*Wc + xi1)*8,
                      (yi1*Wc + xi0)*8, (yi1*Wc + xi1)*8);   // float4 units
}

// Wave-parallel main kernel, 4 barriers; all hot loads channels-last.
__global__ __launch_bounds__(256)
void main_kernel_t(const float* __restrict__ normal_plane,
                   const float* __restrict__ w_reg,
                   const float* __restrict__ w_norm,
                   const float* __restrict__ wsf,
                   float* __restrict__ out) {
    // bijective XCD swizzle: consecutive pix co-resident per XCD -> output
    // lines + gather lines merge in that XCD's L2 (R2: WRITE_SIZE 87.5->10.9MB)
    const int bid = blockIdx.x;
    const int pix = (bid & 7) * (HWc/8) + (bid >> 3);
    const int t = threadIdx.x;
    const int g = t & 7;
    const int d = t >> 3;
    const int lane = t & 63;
    const int wv_id = t >> 6;     // wave index == view index
    const int wl = t & 63;
    const float fxp = (float)(pix % Wc);
    const float fyp = (float)(pix / Wc);

    const float4* srcT0 = (const float4*)(wsf + T_OFF);
    const float4* refT  = (const float4*)(wsf + T_OFF + (size_t)4*Cc*HWc);
    const float*  depT  = wsf + T_OFF + (size_t)5*Cc*HWc;

    __shared__ float4 s_wt[NSRC][Dc];
    __shared__ int4   s_of[NSRC][Dc];
    __shared__ float  s_sd[NSRC][Dc];
    __shared__ float  s_val[NSRC][Dc];
    __shared__ float  s_w[NSRC][Dc];

    // ref fragment: ONE float4 from channels-last layout; fold mean(C//G)
    float4 rv = refT[pix*8 + g];
    rv.x *= 0.25f; rv.y *= 0.25f; rv.z *= 0.25f; rv.w *= 0.25f;
    const float np0 = normal_plane[0*HWc + pix];   // block-uniform broadcasts
    const float np1 = normal_plane[1*HWc + pix];
    const float np2 = normal_plane[2*HWc + pix];
    const float depth_d = depT[(size_t)pix*Dc + d];   // contiguous [pix][32]
    const float wreg_g = w_reg[g];

    // per-view src weights (uniform over threads; static-indexed)
    float srcw[NSRC];
#pragma unroll
    for (int i = 0; i < NSRC; i++) {
        const float* Wv = wsf + 2 + i*15;
        srcw[i] = fmaxf(np0*Wv[12] + np1*Wv[13] + np2*Wv[14], 0.f) + 0.01f;
    }

    // ---- phase 1: parallel weight compute (wave w -> view w) ----
    if (wl < 32)
        compute_wo(fxp, fyp, wsf + 2 + wv_id*15, depT[(size_t)pix*Dc + wl],
                   &s_wt[wv_id][wl], &s_of[wv_id][wl]);
    __syncthreads();

    // ---- phase 2: barrier-free gather + blend stream over all views ----
    float corfeat[NSRC], validv[NSRC];
#pragma unroll
    for (int i = 0; i < NSRC; i++) {
        const float4 wv = s_wt[i][d];
        const int4   ov = s_of[i][d];
        const float4* sp = srcT0 + (size_t)i*HWc*8 + g;
        const float4 v00 = sp[ov.x];
        const float4 v10 = sp[ov.y];
        const float4 v01 = sp[ov.z];
        const float4 v11 = sp[ov.w];
        const float bx = wv.x*v00.x + wv.y*v10.x + wv.z*v01.x + wv.w*v11.x;
        const float by = wv.x*v00.y + wv.y*v10.y + wv.z*v01.y + wv.w*v11.y;
        const float bz = wv.x*v00.z + wv.y*v10.z + wv.z*v01.z + wv.w*v11.z;
        const float bw = wv.x*v00.w + wv.y*v10.w + wv.z*v01.w + wv.w*v11.w;
        corfeat[i] = bx*rv.x + by*rv.y + bz*rv.z + bw*rv.w;

        float sd = corfeat[i];
        sd += __shfl_xor(sd, 1);
        sd += __shfl_xor(sd, 2);
        sd += __shfl_xor(sd, 4);

        const float c0 = __shfl(bx, lane & ~7);   // g==0 lane's channel-0 blend
        validv[i] = (c0 != 0.f) ? 1.f : 0.f;

        if (g == 0) { s_sd[i][d] = sd; s_val[i][d] = validv[i]; }
    }
    __syncthreads();

    // ---- phase 3: parallel softmax (wave w -> view w) + sims ----
    if (wl < 32) {
        const float u = s_sd[wv_id][wl];
        float m = u;
        for (int off = 1; off < 32; off <<= 1) m = fmaxf(m, __shfl_xor(m, off));
        const float e = __expf(u - m);
        float se = e;
        for (int off = 1; off < 32; off <<= 1) se += __shfl_xor(se, off);
        float rse = __builtin_amdgcn_rcpf(se);
        rse = rse * (2.f - se * rse);
        s_w[wv_id][wl] = e * rse * 0.17677669529663687f;  // softmax / sqrt(C)

        const float* Wv = wsf + 2 + wv_id*15;
        const float srcw_w = fmaxf(np0*Wv[12] + np1*Wv[13] + np2*Wv[14], 0.f) + 0.01f;
        float ss = srcw_w * s_val[wv_id][wl];
        for (int off = 1; off < 32; off <<= 1) ss += __shfl_xor(ss, off);
        if (wl == 0) out[OFF_WEIGHT + wv_id*HWc + pix] = ss * (1.f/32.f);
    }
    __syncthreads();

    // ---- phase 4: accumulate (all threads, registers + LDS broadcast) ----
    float acc_cor = 0.f;
    float cws_acc = 1e-8f;
    float sumw_acc = 1e-8f;
    float nval_acc = 0.f;
#pragma unroll
    for (int i = 0; i < NSRC; i++) {
        const float cor_w = s_w[i][d];
        const float sw = srcw[i] * validv[i];
        acc_cor = fmaf(cor_w * sw, corfeat[i], acc_cor);
        cws_acc += cor_w;
        sumw_acc += sw;
        nval_acc += validv[i];
    }

    // finalize: logits = sum_g cf_final*w_reg (8-lane butterfly)
    float r1 = __builtin_amdgcn_rcpf(sumw_acc);
    r1 = r1 * (2.f - sumw_acc * r1);
    float r2 = __builtin_amdgcn_rcpf(cws_acc);
    r2 = r2 * (2.f - cws_acc * r2);
    const float cf_final = acc_cor * r1 * r2;
    float part = cf_final * wreg_g;
    part += __shfl_xor(part, 1);
    part += __shfl_xor(part, 2);
    part += __shfl_xor(part, 4);

    const unsigned int* wsu = (const unsigned int*)wsf;
    const float hmin = __uint_as_float(wsu[0]);
    const float hmax = __uint_as_float(wsu[1]);
    const float hr = hmax - hmin;
    float rhr = __builtin_amdgcn_rcpf(hr);
    rhr = rhr * (2.f - hr * rhr);
    const float logit = part + (depth_d - hmin) * rhr;

    if (g == 0) { s_sd[0][d] = logit; s_val[0][d] = nval_acc; }
    __syncthreads();

    if (t < 32) {
        const float L = s_sd[0][t];
        float m = L;
        for (int off = 1; off < 32; off <<= 1) m = fmaxf(m, __shfl_xor(m, off));
        const float e = __expf(L - m);
        float se = e;
        for (int off = 1; off < 32; off <<= 1) se += __shfl_xor(se, off);
        float rse = __builtin_amdgcn_rcpf(se);
        rse = rse * (2.f - se * rse);
        const float attn = e * rse;

        out[OFF_ATTN + t*HWc + pix] = attn;
        out[OFF_NVAL + t*HWc + pix] = s_val[0][t];

        float av = attn; int ai = t;
        for (int off = 1; off < 32; off <<= 1) {
            float av2 = __shfl_xor(av, off);
            int ai2 = __shfl_xor(ai, off);
            if (av2 > av || (av2 == av && ai2 < ai)) { av = av2; ai = ai2; }
        }
        const float dep = depT[(size_t)pix*Dc + t];
        const float dep_sel = __shfl(dep, ai);
        const float dep0 = __shfl(dep, 0);
        const float dep1 = __shfl(dep, 1);
        if (t == 0) {
            const float last_itv = dep1 - dep0;
            out[OFF_DEPTH + pix] = dep_sel;
            out[OFF_CONF + pix] = av;
            out[OFF_SW + pix] = sumw_acc * 0.25f;   // d==0 lane, /nsrc
            out[OFF_MIN + pix] = dep_sel - last_itv;
            out[OFF_MAX + pix] = dep_sel + last_itv;
        }
    }
    if (t < 3) {
        float v = np0*w_norm[t*3+0] + np1*w_norm[t*3+1] + np2*w_norm[t*3+2];
        out[OFF_EST + t*HWc + pix] = v;
    }
}

// ---------------- fallback path (original, untransposed) ----------------
__global__ void setup_kernel_fb(const float* __restrict__ rotation,
                                const float* __restrict__ proj,
                                float* __restrict__ wsf) {
    if (threadIdx.x != 0 || blockIdx.x != 0) return;
    unsigned int* wsu = (unsigned int*)wsf;
    wsu[0] = 0x7F800000u;
    wsu[1] = 0u;
    setup_body(rotation, proj, wsf);
}

__global__ __launch_bounds__(256)
void minmax_kernel_fb(const float* __restrict__ depth, unsigned int* __restrict__ wsu) {
    const int tid = blockIdx.x * blockDim.x + threadIdx.x;
    const int stride = gridDim.x * blockDim.x;
    const int n4 = (Dc*HWc) / 4;
    const float4* d4 = (const float4*)depth;
    float mn = __uint_as_float(0x7F800000u);
    float mx = 0.f;
    for (int idx = tid; idx < n4; idx += stride) {
        float4 v = d4[idx];
        mn = fminf(mn, fminf(fminf(v.x, v.y), fminf(v.z, v.w)));
        mx = fmaxf(mx, fmaxf(fmaxf(v.x, v.y), fmaxf(v.z, v.w)));
    }
    for (int off = 32; off; off >>= 1) {
        mn = fminf(mn, __shfl_xor(mn, off));
        mx = fmaxf(mx, __shfl_xor(mx, off));
    }
    __shared__ float smn[4], smx[4];
    const int w = threadIdx.x >> 6;
    if ((threadIdx.x & 63) == 0) { smn[w] = mn; smx[w] = mx; }
    __syncthreads();
    if (threadIdx.x == 0) {
        for (int i = 1; i < 4; i++) { mn = fminf(mn, smn[i]); mx = fmaxf(mx, smx[i]); }
        atomicMin(&wsu[0], __float_as_uint(mn));
        atomicMax(&wsu[1], __float_as_uint(mx));
    }
}

__global__ __launch_bounds__(256)
void main_kernel(const float* __restrict__ ref_feature,
                 const float* __restrict__ src_features,
                 const float* __restrict__ normal_plane,
                 const float* __restrict__ depth_hypo,
                 const float* __restrict__ w_reg,
                 const float* __restrict__ w_norm,
                 const float* __restrict__ wsf,
                 float* __restrict__ out) {
    const int pix = blockIdx.x;
    const int t = threadIdx.x;
    const int d = t & 31;
    const int g = t >> 5;
    const float fxp = (float)(pix % Wc);
    const float fyp = (float)(pix / Wc);

    __shared__ float s_cf[Gc*Dc];
    __shared__ float s_valid[Dc];

    float refv[4];
#pragma unroll
    for (int j = 0; j < 4; j++) refv[j] = ref_feature[(g*4+j)*HWc + pix];
    const float np0 = normal_plane[0*HWc + pix];
    const float np1 = normal_plane[1*HWc + pix];
    const float np2 = normal_plane[2*HWc + pix];
    const float depth_d = depth_hypo[d*HWc + pix];
    const float wreg_g = w_reg[g];

    float acc_cor = 0.f;
    float cws_acc = 1e-8f;
    float sumw_acc = 1e-8f;
    float nval_acc = 0.f;

    for (int i = 0; i < NSRC; i++) {
        const float* Wv = wsf + 2 + i*15;
        const float r00=Wv[0], r01=Wv[1], r02=Wv[2];
        const float r10=Wv[3], r11=Wv[4], r12=Wv[5];
        const float r20=Wv[6], r21=Wv[7], r22=Wv[8];
        const float t0=Wv[9], t1=Wv[10], t2=Wv[11];
        const float nv0=Wv[12], nv1=Wv[13], nv2=Wv[14];

        const float b0 = r00*fxp + r01*fyp + r02;
        const float b1 = r10*fxp + r11*fyp + r12;
        const float b2 = r20*fxp + r21*fyp + r22;

        float z = b2*depth_d + t2;
        if (z == 0.f) z = 1e-9f;
        const float px = (b0*depth_d + t0) / z;
        const float py = (b1*depth_d + t1) / z;

        const float fx0 = floorf(px), fy0 = floorf(py);
        const float wx = px - fx0, wy = py - fy0;
        const float fx1 = fx0 + 1.f, fy1 = fy0 + 1.f;
        const bool ix0 = (fx0 >= 0.f) && (fx0 <= (float)(Wc-1));
        const bool ix1 = (fx1 >= 0.f) && (fx1 <= (float)(Wc-1));
        const bool iy0 = (fy0 >= 0.f) && (fy0 <= (float)(Hc-1));
        const bool iy1 = (fy1 >= 0.f) && (fy1 <= (float)(Hc-1));
        const float w00 = (1.f-wx)*(1.f-wy) * ((ix0 && iy0) ? 1.f : 0.f);
        const float w10 = wx*(1.f-wy)       * ((ix1 && iy0) ? 1.f : 0.f);
        const float w01 = (1.f-wx)*wy       * ((ix0 && iy1) ? 1.f : 0.f);
        const float w11 = wx*wy             * ((ix1 && iy1) ? 1.f : 0.f);
        const int xi0 = (int)fminf(fmaxf(fx0, 0.f), (float)(Wc-1));
        const int xi1 = (int)fminf(fmaxf(fx1, 0.f), (float)(Wc-1));
        const int yi0 = (int)fminf(fmaxf(fy0, 0.f), (float)(Hc-1));
        const int yi1 = (int)fminf(fmaxf(fy1, 0.f), (float)(Hc-1));
        const int o00 = yi0*Wc + xi0, o10 = yi0*Wc + xi1;
        const int o01 = yi1*Wc + xi0, o11 = yi1*Wc + xi1;

        const float* src = src_features + (size_t)i * Cc * HWc;
        float corfeat = 0.f;
        float warp0 = 0.f;
#pragma unroll
        for (int j = 0; j < 4; j++) {
            const float* sc = src + (g*4 + j) * HWc;
            float v = w00*sc[o00] + w10*sc[o10] + w01*sc[o01] + w11*sc[o11];
            if (j == 0) warp0 = v;
            corfeat += v * refv[j];
        }
        corfeat *= 0.25f;

        s_cf[t] = corfeat;
        if (g == 0) s_valid[d] = (warp0 != 0.f) ? 1.f : 0.f;
        __syncthreads();

        float s_d = 0.f;
#pragma unroll
        for (int gg = 0; gg < Gc; gg++) s_d += s_cf[gg*32 + d];
        float m = s_d;
        for (int off = 1; off < 32; off <<= 1) m = fmaxf(m, __shfl_xor(m, off));
        float e = expf(s_d - m);
        float se = e;
        for (int off = 1; off < 32; off <<= 1) se += __shfl_xor(se, off);
        const float cor_w = (e / se) * 0.17677669529663687f;

        const float valid = s_valid[d];
        const float src_w = fmaxf(np0*nv0 + np1*nv1 + np2*nv2, 0.f) + 0.01f;
        const float sw = src_w * valid;

        acc_cor += cor_w * sw * corfeat;
        cws_acc += cor_w;
        sumw_acc += sw;
        nval_acc += valid;

        float ssum = sw;
        for (int off = 1; off < 32; off <<= 1) ssum += __shfl_xor(ssum, off);
        if (t == 0) out[OFF_WEIGHT + i*HWc + pix] = ssum * (1.f/32.f);
        __syncthreads();
    }

    const float cf_final = acc_cor / sumw_acc / cws_acc;
    s_cf[t] = cf_final * wreg_g;
    __syncthreads();
    float logit = 0.f;
#pragma unroll
    for (int gg = 0; gg < Gc; gg++) logit += s_cf[gg*32 + d];

    const unsigned int* wsu = (const unsigned int*)wsf;
    const float hmin = __uint_as_float(wsu[0]);
    const float hmax = __uint_as_float(wsu[1]);
    logit += (depth_d - hmin) / (hmax - hmin);

    float m = logit;
    for (int off = 1; off < 32; off <<= 1) m = fmaxf(m, __shfl_xor(m, off));
    float e = expf(logit - m);
    float se = e;
    for (int off = 1; off < 32; off <<= 1) se += __shfl_xor(se, off);
    const float attn = e / se;

    float av = attn; int ai = d;
    for (int off = 1; off < 32; off <<= 1) {
        float av2 = __shfl_xor(av, off);
        int ai2 = __shfl_xor(ai, off);
        if (av2 > av || (av2 == av && ai2 < ai)) { av = av2; ai = ai2; }
    }
    const float dep_sel = __shfl(depth_d, ai, 32);
    const float dep0 = __shfl(depth_d, 0, 32);
    const float dep1 = __shfl(depth_d, 1, 32);
    const float last_itv = dep1 - dep0;

    if (t < 32) {
        out[OFF_ATTN + d*HWc + pix] = attn;
        out[OFF_NVAL + d*HWc + pix] = nval_acc;
    }
    if (t == 0) {
        out[OFF_DEPTH + pix] = dep_sel;
        out[OFF_CONF + pix] = av;
        out[OFF_SW + pix] = sumw_acc * 0.25f;
        out[OFF_MIN + pix] = dep_sel - last_itv;
        out[OFF_MAX + pix] = dep_sel + last_itv;
    }
    if (t < 3) {
        float v = np0*w_norm[t*3+0] + np1*w_norm[t*3+1] + np2*w_norm[t*3+2];
        out[OFF_EST + t*HWc + pix] = v;
    }
}

extern "C" void kernel_launch(void* const* d_in, const int* in_sizes, int n_in,
                              void* d_out, int out_size, void* d_ws, size_t ws_size,
                              hipStream_t stream) {
    const float* ref   = (const float*)d_in[0];
    const float* src   = (const float*)d_in[1];
    const float* rot   = (const float*)d_in[2];
    const float* np_   = (const float*)d_in[3];
    const float* proj  = (const float*)d_in[4];
    const float* dh    = (const float*)d_in[5];
    const float* wreg  = (const float*)d_in[6];
    const float* wnorm = (const float*)d_in[7];
    float* out = (float*)d_out;
    float* ws  = (float*)d_ws;

    // init hmin (uint-min: 0xFFFFFFFF) / hmax (0) for the fused atomics
    hipMemsetAsync((char*)d_ws + 0, 0xFF, 4, stream);
    hipMemsetAsync((char*)d_ws + 4, 0x00, 4, stream);

    const size_t need = (size_t)(T_OFF + (size_t)6*Cc*HWc) * sizeof(float);
    if (ws_size >= need) {
        dim3 tg(HWc/64, 6);
        prep_kernel<<<tg, 256, 0, stream>>>(src, ref, dh, rot, proj, ws);
        main_kernel_t<<<HWc, 256, 0, stream>>>(np_, wreg, wnorm, ws, out);
    } else {
        setup_kernel_fb<<<1, 1, 0, stream>>>(rot, proj, ws);
        minmax_kernel_fb<<<64, 256, 0, stream>>>(dh, (unsigned int*)ws);
        main_kernel<<<HWc, 256, 0, stream>>>(ref, src, np_, dh, wreg, wnorm, ws, out);
    }
}

// Round 5
// 194.763 us; speedup vs baseline: 1.2733x; 1.0993x over previous
//
#include <hip/hip_runtime.h>
#include <math.h>

#define Vc 5
#define Cc 32
#define Gc 8
#define Dc 32
#define Hc 192
#define Wc 192
#define HWc (Hc*Wc)
#define NSRC (Vc-1)
#define NTILE (HWc/64)   // 576

// output offsets (floats)
#define OFF_DEPTH  0
#define OFF_CONF   (HWc)
#define OFF_ATTN   (2*HWc)
#define OFF_EST    (OFF_ATTN + Dc*HWc)
#define OFF_SW     (OFF_EST + 3*HWc)
#define OFF_WEIGHT (OFF_SW + HWc)
#define OFF_NVAL   (OFF_WEIGHT + NSRC*HWc)
#define OFF_MIN    (OFF_NVAL + Dc*HWc)
#define OFF_MAX    (OFF_MIN + HWc)

// ws layout (floats):
//   [0]=hmin [1]=hmax (plain floats, written by reduce_kernel)
//   [2 + i*15]: rot(9), trans(3), norv(3)
//   [T_OFF]: channels-last images, img=0..3 src, 4 ref, 5 depth ([HW][32] each)
//   [PART_OFF]: 576 partial (min,max) pairs from prep depth blocks
//   [NP_OFF]: normal_plane packed [HW][4]
#define T_OFF 64
#define PART_OFF (T_OFF + 6*Cc*HWc)
#define NP_OFF (PART_OFF + 2*NTILE)

__device__ void inv4(const float* A, float* out) {
    float M[4][8];
    for (int r = 0; r < 4; r++) {
        for (int c = 0; c < 4; c++) { M[r][c] = A[r*4+c]; M[r][c+4] = (r == c) ? 1.f : 0.f; }
    }
    for (int col = 0; col < 4; col++) {
        int piv = col; float best = fabsf(M[col][col]);
        for (int r = col+1; r < 4; r++) { float v = fabsf(M[r][col]); if (v > best) { best = v; piv = r; } }
        if (piv != col) for (int c = 0; c < 8; c++) { float t = M[col][c]; M[col][c] = M[piv][c]; M[piv][c] = t; }
        float inv = 1.f / M[col][col];
        for (int c = 0; c < 8; c++) M[col][c] *= inv;
        for (int r = 0; r < 4; r++) {
            if (r == col) continue;
            float f = M[r][col];
            for (int c = 0; c < 8; c++) M[r][c] -= f * M[col][c];
        }
    }
    for (int r = 0; r < 4; r++) for (int c = 0; c < 4; c++) out[r*4+c] = M[r][c+4];
}

__device__ void inv3(const float* A, float* out) {
    float a=A[0],b=A[1],c=A[2],d=A[3],e=A[4],f=A[5],g=A[6],h=A[7],i=A[8];
    float det = a*(e*i-f*h) - b*(d*i-f*g) + c*(d*h-e*g);
    float id = 1.f/det;
    out[0]=(e*i-f*h)*id; out[1]=(c*h-b*i)*id; out[2]=(b*f-c*e)*id;
    out[3]=(f*g-d*i)*id; out[4]=(a*i-c*g)*id; out[5]=(c*d-a*f)*id;
    out[6]=(d*h-e*g)*id; out[7]=(b*g-a*h)*id; out[8]=(a*e-b*d)*id;
}

__device__ void setup_body(const float* __restrict__ rotation,
                           const float* __restrict__ proj,
                           float* __restrict__ wsf) {
    float refE[16], refK[16], refNew[16], invRef[16];
    for (int k = 0; k < 16; k++) { refE[k] = proj[k]; refK[k] = proj[16+k]; }
    for (int k = 0; k < 16; k++) refNew[k] = refE[k];
    for (int r = 0; r < 3; r++) for (int c = 0; c < 4; c++) {
        float s = 0.f;
        for (int k = 0; k < 3; k++) s += refK[r*4+k] * refE[k*4+c];
        refNew[r*4+c] = s;
    }
    inv4(refNew, invRef);
    float invR0[9];
    inv3(rotation, invR0);

    for (int i = 0; i < NSRC; i++) {
        const float* E = proj + (i+1)*32;
        const float* K = proj + (i+1)*32 + 16;
        float sNew[16];
        for (int k = 0; k < 16; k++) sNew[k] = E[k];
        for (int r = 0; r < 3; r++) for (int c = 0; c < 4; c++) {
            float s = 0.f;
            for (int k = 0; k < 3; k++) s += K[r*4+k] * E[k*4+c];
            sNew[r*4+c] = s;
        }
        float P[16];
        for (int r = 0; r < 4; r++) for (int c = 0; c < 4; c++) {
            float s = 0.f;
            for (int k = 0; k < 4; k++) s += sNew[r*4+k] * invRef[k*4+c];
            P[r*4+c] = s;
        }
        float* o = wsf + 2 + i*15;
        for (int r = 0; r < 3; r++) for (int c = 0; c < 3; c++) o[r*3+c] = P[r*4+c];
        for (int r = 0; r < 3; r++) o[9+r] = P[r*4+3];
        const float* Ri = rotation + (i+1)*9;
        for (int c = 0; c < 3; c++) {
            float s = 0.f;
            for (int k = 0; k < 3; k++) s += Ri[2*3+k] * invR0[k*3+c];
            o[12+c] = s;
        }
    }
}

// Fused prep:
//  img 0..3: src [C][HW]->[HW][C];  img 4: ref;  img 5: depth (+ partial
//  min/max, plain stores -> no atomics, no memset init);  img 6: normal_plane
//  packed [HW][4]. Matrix setup rides on block (0, img0) thread 0.
__global__ __launch_bounds__(256)
void prep_kernel(const float* __restrict__ src,
                 const float* __restrict__ ref,
                 const float* __restrict__ depth,
                 const float* __restrict__ normal,
                 const float* __restrict__ rotation,
                 const float* __restrict__ proj,
                 float* __restrict__ wsf) {
    const int img = blockIdx.y;          // 0..6
    const int p0  = blockIdx.x * 64;
    const int t = threadIdx.x;

    if (img == 6) {  // normal_plane [3][HW] -> [HW][4]
        __shared__ float tl[3][64];
        if (t < 192) { const int c = t >> 6, p = t & 63; tl[c][p] = normal[c*HWc + p0 + p]; }
        __syncthreads();
        const int p = t >> 2, c = t & 3;
        wsf[NP_OFF + (size_t)(p0 + p)*4 + c] = (c < 3) ? tl[c][p] : 0.f;
        return;
    }

    const float* in = (img < NSRC) ? (src + (size_t)img*Cc*HWc)
                    : (img == NSRC) ? ref : depth;
    float* outp = wsf + T_OFF + (size_t)img * Cc * HWc;
    __shared__ float tile[Cc][64+1];
    float mn = __uint_as_float(0x7F800000u);
    float mx = 0.f;
#pragma unroll
    for (int k = 0; k < 8; k++) {
        const int c = (t >> 6) + k*4;
        const int p = t & 63;
        const float v = in[(size_t)c*HWc + p0 + p];
        tile[c][p] = v;
        mn = fminf(mn, v);
        mx = fmaxf(mx, v);
    }
    __syncthreads();
#pragma unroll
    for (int k = 0; k < 8; k++) {
        const int c = t & 31;
        const int p = (t >> 5) + k*8;
        outp[(size_t)(p0 + p)*Cc + c] = tile[c][p];
    }
    if (img == 5) {   // depth tile: partial min/max, one pair per block
        for (int off = 32; off; off >>= 1) {
            mn = fminf(mn, __shfl_xor(mn, off));
            mx = fmaxf(mx, __shfl_xor(mx, off));
        }
        __shared__ float smn[4], smx[4];
        const int w = t >> 6;
        if ((t & 63) == 0) { smn[w] = mn; smx[w] = mx; }
        __syncthreads();
        if (t == 0) {
            for (int i = 1; i < 4; i++) { mn = fminf(mn, smn[i]); mx = fmaxf(mx, smx[i]); }
            wsf[PART_OFF + blockIdx.x*2 + 0] = mn;
            wsf[PART_OFF + blockIdx.x*2 + 1] = mx;
        }
    }
    if (img == 0 && blockIdx.x == 0 && t == 0)
        setup_body(rotation, proj, wsf);
}

// 1-block finalize: reduce 576 partial pairs -> ws[0]=hmin, ws[1]=hmax.
__global__ __launch_bounds__(256)
void reduce_kernel(float* __restrict__ wsf) {
    const int t = threadIdx.x;
    float mn = __uint_as_float(0x7F800000u);
    float mx = 0.f;
    for (int idx = t; idx < NTILE; idx += 256) {
        mn = fminf(mn, wsf[PART_OFF + idx*2 + 0]);
        mx = fmaxf(mx, wsf[PART_OFF + idx*2 + 1]);
    }
    for (int off = 32; off; off >>= 1) {
        mn = fminf(mn, __shfl_xor(mn, off));
        mx = fmaxf(mx, __shfl_xor(mx, off));
    }
    __shared__ float smn[4], smx[4];
    const int w = t >> 6;
    if ((t & 63) == 0) { smn[w] = mn; smx[w] = mx; }
    __syncthreads();
    if (t == 0) {
        for (int i = 1; i < 4; i++) { mn = fminf(mn, smn[i]); mx = fmaxf(mx, smx[i]); }
        wsf[0] = mn;
        wsf[1] = mx;
    }
}

// Bilinear weight + pre-scaled tap-offset computation (uses Wv[0..11] only).
__device__ __forceinline__ void compute_wo(float fxp, float fyp, const float* __restrict__ Wv,
                                           float dep, float4* wout, int4* oout) {
    const float b0 = Wv[0]*fxp + Wv[1]*fyp + Wv[2];
    const float b1 = Wv[3]*fxp + Wv[4]*fyp + Wv[5];
    const float b2 = Wv[6]*fxp + Wv[7]*fyp + Wv[8];
    float z = fmaf(b2, dep, Wv[11]);
    if (z == 0.f) z = 1e-9f;
    float rz = __builtin_amdgcn_rcpf(z);
    rz = rz * (2.f - z * rz);                 // Newton refine
    const float px = fmaf(b0, dep, Wv[9])  * rz;
    const float py = fmaf(b1, dep, Wv[10]) * rz;

    const float fx0 = floorf(px), fy0 = floorf(py);
    const float wx = px - fx0, wy = py - fy0;
    const float fx1 = fx0 + 1.f, fy1 = fy0 + 1.f;
    const bool ix0 = (fx0 >= 0.f) && (fx0 <= (float)(Wc-1));
    const bool ix1 = (fx1 >= 0.f) && (fx1 <= (float)(Wc-1));
    const bool iy0 = (fy0 >= 0.f) && (fy0 <= (float)(Hc-1));
    const bool iy1 = (fy1 >= 0.f) && (fy1 <= (float)(Hc-1));
    const float w00 = (1.f-wx)*(1.f-wy) * ((ix0 && iy0) ? 1.f : 0.f);
    const float w10 = wx*(1.f-wy)       * ((ix1 && iy0) ? 1.f : 0.f);
    const float w01 = (1.f-wx)*wy       * ((ix0 && iy1) ? 1.f : 0.f);
    const float w11 = wx*wy             * ((ix1 && iy1) ? 1.f : 0.f);
    const int xi0 = (int)fminf(fmaxf(fx0, 0.f), (float)(Wc-1));
    const int xi1 = (int)fminf(fmaxf(fx1, 0.f), (float)(Wc-1));
    const int yi0 = (int)fminf(fmaxf(fy0, 0.f), (float)(Hc-1));
    const int yi1 = (int)fminf(fmaxf(fy1, 0.f), (float)(Hc-1));
    *wout = make_float4(w00, w10, w01, w11);
    *oout = make_int4((yi0*Wc + xi0)*8, (yi0*Wc + xi1)*8,
                      (yi1*Wc + xi0)*8, (yi1*Wc + xi1)*8);   // float4 units
}

// Wave-parallel main kernel. Dense phases: waves 0-1 each own 2 views with
// all 64 lanes active (v = 2*wv + (wl>>5), d = wl&31); waves 2-3 skip via
// execz branch. Per-thread srcw/valid work moved to phase 3 -> LDS.
template<bool USE_NPT>
__global__ __launch_bounds__(256)
void main_kernel_t(const float* __restrict__ normal_plane,
                   const float* __restrict__ w_reg,
                   const float* __restrict__ w_norm,
                   const float* __restrict__ wsf,
                   float* __restrict__ out) {
    // bijective XCD swizzle: consecutive pix co-resident per XCD
    const int bid = blockIdx.x;
    const int pix = (bid & 7) * (HWc/8) + (bid >> 3);
    const int t = threadIdx.x;
    const int g = t & 7;
    const int d = t >> 3;
    const int wv_id = t >> 6;
    const int wl = t & 63;
    const float fxp = (float)(pix % Wc);
    const float fyp = (float)(pix / Wc);

    const float4* srcT0 = (const float4*)(wsf + T_OFF);
    const float4* refT  = (const float4*)(wsf + T_OFF + (size_t)4*Cc*HWc);
    const float*  depT  = wsf + T_OFF + (size_t)5*Cc*HWc;

    __shared__ float4 s_wt[NSRC][Dc];
    __shared__ int4   s_of[NSRC][Dc];
    __shared__ float  s_sd[NSRC][Dc];
    __shared__ float  s_val[NSRC][Dc];
    __shared__ float  s_w[NSRC][Dc];
    __shared__ float  s_sw[NSRC][Dc];

    // ref fragment: ONE float4; fold mean(C//G)
    float4 rv = refT[pix*8 + g];
    rv.x *= 0.25f; rv.y *= 0.25f; rv.z *= 0.25f; rv.w *= 0.25f;
    float np0, np1, np2;
    if (USE_NPT) {
        const float4 npv = ((const float4*)(wsf + NP_OFF))[pix];
        np0 = npv.x; np1 = npv.y; np2 = npv.z;
    } else {
        np0 = normal_plane[0*HWc + pix];
        np1 = normal_plane[1*HWc + pix];
        np2 = normal_plane[2*HWc + pix];
    }
    const float depth_d = depT[(size_t)pix*Dc + d];
    const float wreg_g = w_reg[g];

    // ---- phase 1 (dense): waves 0-1, 2 views/wave, 64 lanes active ----
    if (wv_id < 2) {
        const int v0 = wv_id << 1;
        const int vv = v0 | (wl >> 5);
        const int dd = wl & 31;
        const float* Wa = wsf + 2 + v0*15;      // wave-uniform -> s_load
        const float* Wb = Wa + 15;
        float Wv[12];
#pragma unroll
        for (int k = 0; k < 12; k++) Wv[k] = (wl < 32) ? Wa[k] : Wb[k];
        compute_wo(fxp, fyp, Wv, depT[(size_t)pix*Dc + dd],
                   &s_wt[vv][dd], &s_of[vv][dd]);
    }
    __syncthreads();

    // ---- phase 2: barrier-free gather + blend stream over all views ----
    float corfeat[NSRC];
#pragma unroll
    for (int i = 0; i < NSRC; i++) {
        const float4 wv = s_wt[i][d];
        const int4   ov = s_of[i][d];
        const float4* sp = srcT0 + (size_t)i*HWc*8 + g;
        const float4 v00 = sp[ov.x];
        const float4 v10 = sp[ov.y];
        const float4 v01 = sp[ov.z];
        const float4 v11 = sp[ov.w];
        const float bx = wv.x*v00.x + wv.y*v10.x + wv.z*v01.x + wv.w*v11.x;
        const float by = wv.x*v00.y + wv.y*v10.y + wv.z*v01.y + wv.w*v11.y;
        const float bz = wv.x*v00.z + wv.y*v10.z + wv.z*v01.z + wv.w*v11.z;
        const float bw = wv.x*v00.w + wv.y*v10.w + wv.z*v01.w + wv.w*v11.w;
        corfeat[i] = bx*rv.x + by*rv.y + bz*rv.z + bw*rv.w;

        float sd = corfeat[i];
        sd += __shfl_xor(sd, 1);
        sd += __shfl_xor(sd, 2);
        sd += __shfl_xor(sd, 4);

        // g==0 lane's bx IS channel 0 of the blend -> valid flag
        if (g == 0) { s_sd[i][d] = sd; s_val[i][d] = (bx != 0.f) ? 1.f : 0.f; }
    }
    __syncthreads();

    // ---- phase 3 (dense): softmax over d + srcw*valid + sims, waves 0-1 ----
    if (wv_id < 2) {
        const int v0 = wv_id << 1;
        const int vv = v0 | (wl >> 5);
        const int dd = wl & 31;
        const float u = s_sd[vv][dd];
        float m = u;
        for (int off = 1; off < 32; off <<= 1) m = fmaxf(m, __shfl_xor(m, off));
        const float e = __expf(u - m);
        float se = e;
        for (int off = 1; off < 32; off <<= 1) se += __shfl_xor(se, off);
        float rse = __builtin_amdgcn_rcpf(se);
        rse = rse * (2.f - se * rse);
        s_w[vv][dd] = e * rse * 0.17677669529663687f;  // softmax / sqrt(C)

        const float* Na = wsf + 2 + v0*15 + 12;   // wave-uniform norv triples
        const float* Nb = Na + 15;
        const float n0 = (wl < 32) ? Na[0] : Nb[0];
        const float n1 = (wl < 32) ? Na[1] : Nb[1];
        const float n2 = (wl < 32) ? Na[2] : Nb[2];
        const float srcw_v = fmaxf(np0*n0 + np1*n1 + np2*n2, 0.f) + 0.01f;
        const float swv = srcw_v * s_val[vv][dd];
        s_sw[vv][dd] = swv;
        float ss = swv;
        for (int off = 1; off < 32; off <<= 1) ss += __shfl_xor(ss, off);
        if ((wl & 31) == 0) out[OFF_WEIGHT + vv*HWc + pix] = ss * (1.f/32.f);
    }
    __syncthreads();

    // ---- phase 4: accumulate (all threads; LDS broadcasts + registers) ----
    float acc_cor = 0.f;
    float cws_acc = 1e-8f;
    float sumw_acc = 1e-8f;
#pragma unroll
    for (int i = 0; i < NSRC; i++) {
        const float cor_w = s_w[i][d];
        const float sw = s_sw[i][d];
        acc_cor = fmaf(cor_w * sw, corfeat[i], acc_cor);
        cws_acc += cor_w;
        sumw_acc += sw;
    }

    // finalize: logits = sum_g cf_final*w_reg (8-lane butterfly)
    float r1 = __builtin_amdgcn_rcpf(sumw_acc);
    r1 = r1 * (2.f - sumw_acc * r1);
    float r2 = __builtin_amdgcn_rcpf(cws_acc);
    r2 = r2 * (2.f - cws_acc * r2);
    const float cf_final = acc_cor * r1 * r2;
    float part = cf_final * wreg_g;
    part += __shfl_xor(part, 1);
    part += __shfl_xor(part, 2);
    part += __shfl_xor(part, 4);

    const float hmin = wsf[0];
    const float hmax = wsf[1];
    const float hr = hmax - hmin;
    float rhr = __builtin_amdgcn_rcpf(hr);
    rhr = rhr * (2.f - hr * rhr);
    const float logit = part + (depth_d - hmin) * rhr;

    if (g == 0) s_sd[0][d] = logit;
    __syncthreads();

    if (t < 32) {
        const float L = s_sd[0][t];
        float m = L;
        for (int off = 1; off < 32; off <<= 1) m = fmaxf(m, __shfl_xor(m, off));
        const float e = __expf(L - m);
        float se = e;
        for (int off = 1; off < 32; off <<= 1) se += __shfl_xor(se, off);
        float rse = __builtin_amdgcn_rcpf(se);
        rse = rse * (2.f - se * rse);
        const float attn = e * rse;

        const float nval = s_val[0][t] + s_val[1][t] + s_val[2][t] + s_val[3][t];
        out[OFF_ATTN + t*HWc + pix] = attn;
        out[OFF_NVAL + t*HWc + pix] = nval;

        float av = attn; int ai = t;
        for (int off = 1; off < 32; off <<= 1) {
            float av2 = __shfl_xor(av, off);
            int ai2 = __shfl_xor(ai, off);
            if (av2 > av || (av2 == av && ai2 < ai)) { av = av2; ai = ai2; }
        }
        const float dep = depT[(size_t)pix*Dc + t];
        const float dep_sel = __shfl(dep, ai);
        const float dep0 = __shfl(dep, 0);
        const float dep1 = __shfl(dep, 1);
        if (t == 0) {
            const float last_itv = dep1 - dep0;
            out[OFF_DEPTH + pix] = dep_sel;
            out[OFF_CONF + pix] = av;
            out[OFF_SW + pix] = sumw_acc * 0.25f;   // d==0 lane, /nsrc
            out[OFF_MIN + pix] = dep_sel - last_itv;
            out[OFF_MAX + pix] = dep_sel + last_itv;
        }
    }
    if (t < 3) {
        float v = np0*w_norm[t*3+0] + np1*w_norm[t*3+1] + np2*w_norm[t*3+2];
        out[OFF_EST + t*HWc + pix] = v;
    }
}

// ---------------- fallback path (original, untransposed) ----------------
__global__ void setup_kernel_fb(const float* __restrict__ rotation,
                                const float* __restrict__ proj,
                                float* __restrict__ wsf) {
    if (threadIdx.x != 0 || blockIdx.x != 0) return;
    unsigned int* wsu = (unsigned int*)wsf;
    wsu[0] = 0x7F800000u;
    wsu[1] = 0u;
    setup_body(rotation, proj, wsf);
}

__global__ __launch_bounds__(256)
void minmax_kernel_fb(const float* __restrict__ depth, unsigned int* __restrict__ wsu) {
    const int tid = blockIdx.x * blockDim.x + threadIdx.x;
    const int stride = gridDim.x * blockDim.x;
    const int n4 = (Dc*HWc) / 4;
    const float4* d4 = (const float4*)depth;
    float mn = __uint_as_float(0x7F800000u);
    float mx = 0.f;
    for (int idx = tid; idx < n4; idx += stride) {
        float4 v = d4[idx];
        mn = fminf(mn, fminf(fminf(v.x, v.y), fminf(v.z, v.w)));
        mx = fmaxf(mx, fmaxf(fmaxf(v.x, v.y), fmaxf(v.z, v.w)));
    }
    for (int off = 32; off; off >>= 1) {
        mn = fminf(mn, __shfl_xor(mn, off));
        mx = fmaxf(mx, __shfl_xor(mx, off));
    }
    __shared__ float smn[4], smx[4];
    const int w = threadIdx.x >> 6;
    if ((threadIdx.x & 63) == 0) { smn[w] = mn; smx[w] = mx; }
    __syncthreads();
    if (threadIdx.x == 0) {
        for (int i = 1; i < 4; i++) { mn = fminf(mn, smn[i]); mx = fmaxf(mx, smx[i]); }
        atomicMin(&wsu[0], __float_as_uint(mn));
        atomicMax(&wsu[1], __float_as_uint(mx));
        // convert to plain floats for the shared epilogue convention
    }
}

__global__ __launch_bounds__(256)
void main_kernel(const float* __restrict__ ref_feature,
                 const float* __restrict__ src_features,
                 const float* __restrict__ normal_plane,
                 const float* __restrict__ depth_hypo,
                 const float* __restrict__ w_reg,
                 const float* __restrict__ w_norm,
                 const float* __restrict__ wsf,
                 float* __restrict__ out) {
    const int pix = blockIdx.x;
    const int t = threadIdx.x;
    const int d = t & 31;
    const int g = t >> 5;
    const float fxp = (float)(pix % Wc);
    const float fyp = (float)(pix / Wc);

    __shared__ float s_cf[Gc*Dc];
    __shared__ float s_valid[Dc];

    float refv[4];
#pragma unroll
    for (int j = 0; j < 4; j++) refv[j] = ref_feature[(g*4+j)*HWc + pix];
    const float np0 = normal_plane[0*HWc + pix];
    const float np1 = normal_plane[1*HWc + pix];
    const float np2 = normal_plane[2*HWc + pix];
    const float depth_d = depth_hypo[d*HWc + pix];
    const float wreg_g = w_reg[g];

    float acc_cor = 0.f;
    float cws_acc = 1e-8f;
    float sumw_acc = 1e-8f;
    float nval_acc = 0.f;

    for (int i = 0; i < NSRC; i++) {
        const float* Wv = wsf + 2 + i*15;
        const float r00=Wv[0], r01=Wv[1], r02=Wv[2];
        const float r10=Wv[3], r11=Wv[4], r12=Wv[5];
        const float r20=Wv[6], r21=Wv[7], r22=Wv[8];
        const float t0=Wv[9], t1=Wv[10], t2=Wv[11];
        const float nv0=Wv[12], nv1=Wv[13], nv2=Wv[14];

        const float b0 = r00*fxp + r01*fyp + r02;
        const float b1 = r10*fxp + r11*fyp + r12;
        const float b2 = r20*fxp + r21*fyp + r22;

        float z = b2*depth_d + t2;
        if (z == 0.f) z = 1e-9f;
        const float px = (b0*depth_d + t0) / z;
        const float py = (b1*depth_d + t1) / z;

        const float fx0 = floorf(px), fy0 = floorf(py);
        const float wx = px - fx0, wy = py - fy0;
        const float fx1 = fx0 + 1.f, fy1 = fy0 + 1.f;
        const bool ix0 = (fx0 >= 0.f) && (fx0 <= (float)(Wc-1));
        const bool ix1 = (fx1 >= 0.f) && (fx1 <= (float)(Wc-1));
        const bool iy0 = (fy0 >= 0.f) && (fy0 <= (float)(Hc-1));
        const bool iy1 = (fy1 >= 0.f) && (fy1 <= (float)(Hc-1));
        const float w00 = (1.f-wx)*(1.f-wy) * ((ix0 && iy0) ? 1.f : 0.f);
        const float w10 = wx*(1.f-wy)       * ((ix1 && iy0) ? 1.f : 0.f);
        const float w01 = (1.f-wx)*wy       * ((ix0 && iy1) ? 1.f : 0.f);
        const float w11 = wx*wy             * ((ix1 && iy1) ? 1.f : 0.f);
        const int xi0 = (int)fminf(fmaxf(fx0, 0.f), (float)(Wc-1));
        const int xi1 = (int)fminf(fmaxf(fx1, 0.f), (float)(Wc-1));
        const int yi0 = (int)fminf(fmaxf(fy0, 0.f), (float)(Hc-1));
        const int yi1 = (int)fminf(fmaxf(fy1, 0.f), (float)(Hc-1));
        const int o00 = yi0*Wc + xi0, o10 = yi0*Wc + xi1;
        const int o01 = yi1*Wc + xi0, o11 = yi1*Wc + xi1;

        const float* src = src_features + (size_t)i * Cc * HWc;
        float corfeat = 0.f;
        float warp0 = 0.f;
#pragma unroll
        for (int j = 0; j < 4; j++) {
            const float* sc = src + (g*4 + j) * HWc;
            float v = w00*sc[o00] + w10*sc[o10] + w01*sc[o01] + w11*sc[o11];
            if (j == 0) warp0 = v;
            corfeat += v * refv[j];
        }
        corfeat *= 0.25f;

        s_cf[t] = corfeat;
        if (g == 0) s_valid[d] = (warp0 != 0.f) ? 1.f : 0.f;
        __syncthreads();

        float s_d = 0.f;
#pragma unroll
        for (int gg = 0; gg < Gc; gg++) s_d += s_cf[gg*32 + d];
        float m = s_d;
        for (int off = 1; off < 32; off <<= 1) m = fmaxf(m, __shfl_xor(m, off));
        float e = expf(s_d - m);
        float se = e;
        for (int off = 1; off < 32; off <<= 1) se += __shfl_xor(se, off);
        const float cor_w = (e / se) * 0.17677669529663687f;

        const float valid = s_valid[d];
        const float src_w = fmaxf(np0*nv0 + np1*nv1 + np2*nv2, 0.f) + 0.01f;
        const float sw = src_w * valid;

        acc_cor += cor_w * sw * corfeat;
        cws_acc += cor_w;
        sumw_acc += sw;
        nval_acc += valid;

        float ssum = sw;
        for (int off = 1; off < 32; off <<= 1) ssum += __shfl_xor(ssum, off);
        if (t == 0) out[OFF_WEIGHT + i*HWc + pix] = ssum * (1.f/32.f);
        __syncthreads();
    }

    const float cf_final = acc_cor / sumw_acc / cws_acc;
    s_cf[t] = cf_final * wreg_g;
    __syncthreads();
    float logit = 0.f;
#pragma unroll
    for (int gg = 0; gg < Gc; gg++) logit += s_cf[gg*32 + d];

    const unsigned int* wsu = (const unsigned int*)wsf;
    const float hmin = __uint_as_float(wsu[0]);
    const float hmax = __uint_as_float(wsu[1]);
    logit += (depth_d - hmin) / (hmax - hmin);

    float m = logit;
    for (int off = 1; off < 32; off <<= 1) m = fmaxf(m, __shfl_xor(m, off));
    float e = expf(logit - m);
    float se = e;
    for (int off = 1; off < 32; off <<= 1) se += __shfl_xor(se, off);
    const float attn = e / se;

    float av = attn; int ai = d;
    for (int off = 1; off < 32; off <<= 1) {
        float av2 = __shfl_xor(av, off);
        int ai2 = __shfl_xor(ai, off);
        if (av2 > av || (av2 == av && ai2 < ai)) { av = av2; ai = ai2; }
    }
    const float dep_sel = __shfl(depth_d, ai, 32);
    const float dep0 = __shfl(depth_d, 0, 32);
    const float dep1 = __shfl(depth_d, 1, 32);
    const float last_itv = dep1 - dep0;

    if (t < 32) {
        out[OFF_ATTN + d*HWc + pix] = attn;
        out[OFF_NVAL + d*HWc + pix] = nval_acc;
    }
    if (t == 0) {
        out[OFF_DEPTH + pix] = dep_sel;
        out[OFF_CONF + pix] = av;
        out[OFF_SW + pix] = sumw_acc * 0.25f;
        out[OFF_MIN + pix] = dep_sel - last_itv;
        out[OFF_MAX + pix] = dep_sel + last_itv;
    }
    if (t < 3) {
        float v = np0*w_norm[t*3+0] + np1*w_norm[t*3+1] + np2*w_norm[t*3+2];
        out[OFF_EST + t*HWc + pix] = v;
    }
}

extern "C" void kernel_launch(void* const* d_in, const int* in_sizes, int n_in,
                              void* d_out, int out_size, void* d_ws, size_t ws_size,
                              hipStream_t stream) {
    const float* ref   = (const float*)d_in[0];
    const float* src   = (const float*)d_in[1];
    const float* rot   = (const float*)d_in[2];
    const float* np_   = (const float*)d_in[3];
    const float* proj  = (const float*)d_in[4];
    const float* dh    = (const float*)d_in[5];
    const float* wreg  = (const float*)d_in[6];
    const float* wnorm = (const float*)d_in[7];
    float* out = (float*)d_out;
    float* ws  = (float*)d_ws;

    const size_t need_np   = (size_t)(NP_OFF + 4*HWc) * sizeof(float);
    const size_t need_base = (size_t)NP_OFF * sizeof(float);

    if (ws_size >= need_np) {
        dim3 tg(NTILE, 7);
        prep_kernel<<<tg, 256, 0, stream>>>(src, ref, dh, np_, rot, proj, ws);
        reduce_kernel<<<1, 256, 0, stream>>>(ws);
        main_kernel_t<true><<<HWc, 256, 0, stream>>>(np_, wreg, wnorm, ws, out);
    } else if (ws_size >= need_base) {
        dim3 tg(NTILE, 6);
        prep_kernel<<<tg, 256, 0, stream>>>(src, ref, dh, np_, rot, proj, ws);
        reduce_kernel<<<1, 256, 0, stream>>>(ws);
        main_kernel_t<false><<<HWc, 256, 0, stream>>>(np_, wreg, wnorm, ws, out);
    } else {
        hipMemsetAsync((char*)d_ws + 0, 0xFF, 4, stream);
        hipMemsetAsync((char*)d_ws + 4, 0x00, 4, stream);
        setup_kernel_fb<<<1, 1, 0, stream>>>(rot, proj, ws);
        minmax_kernel_fb<<<64, 256, 0, stream>>>(dh, (unsigned int*)ws);
        main_kernel<<<HWc, 256, 0, stream>>>(ref, src, np_, dh, wreg, wnorm, ws, out);
    }
}

// Round 6
// 191.513 us; speedup vs baseline: 1.2949x; 1.0170x over previous
//
#include <hip/hip_runtime.h>
#include <math.h>

#define Vc 5
#define Cc 32
#define Gc 8
#define Dc 32
#define Hc 192
#define Wc 192
#define HWc (Hc*Wc)
#define NSRC (Vc-1)
#define NTILE (HWc/64)   // 576

// output offsets (floats)
#define OFF_DEPTH  0
#define OFF_CONF   (HWc)
#define OFF_ATTN   (2*HWc)
#define OFF_EST    (OFF_ATTN + Dc*HWc)
#define OFF_SW     (OFF_EST + 3*HWc)
#define OFF_WEIGHT (OFF_SW + HWc)
#define OFF_NVAL   (OFF_WEIGHT + NSRC*HWc)
#define OFF_MIN    (OFF_NVAL + Dc*HWc)
#define OFF_MAX    (OFF_MIN + HWc)

// ws layout (floats):
//   [0]=hmin [1]=hmax (fallback path only)
//   [2 + i*15]: rot(9), trans(3), norv(3)
//   [T_OFF]: channels-last images, img=0..3 src, 4 ref, 5 depth ([HW][32] each)
//   [PART_OFF]: 576 partial (min,max) pairs from prep depth blocks
//   [NP_OFF]: normal_plane packed [HW][4]
#define T_OFF 64
#define PART_OFF (T_OFF + 6*Cc*HWc)
#define NP_OFF (PART_OFF + 2*NTILE)

__device__ void inv4(const float* A, float* out) {
    float M[4][8];
    for (int r = 0; r < 4; r++) {
        for (int c = 0; c < 4; c++) { M[r][c] = A[r*4+c]; M[r][c+4] = (r == c) ? 1.f : 0.f; }
    }
    for (int col = 0; col < 4; col++) {
        int piv = col; float best = fabsf(M[col][col]);
        for (int r = col+1; r < 4; r++) { float v = fabsf(M[r][col]); if (v > best) { best = v; piv = r; } }
        if (piv != col) for (int c = 0; c < 8; c++) { float t = M[col][c]; M[col][c] = M[piv][c]; M[piv][c] = t; }
        float inv = 1.f / M[col][col];
        for (int c = 0; c < 8; c++) M[col][c] *= inv;
        for (int r = 0; r < 4; r++) {
            if (r == col) continue;
            float f = M[r][col];
            for (int c = 0; c < 8; c++) M[r][c] -= f * M[col][c];
        }
    }
    for (int r = 0; r < 4; r++) for (int c = 0; c < 4; c++) out[r*4+c] = M[r][c+4];
}

__device__ void inv3(const float* A, float* out) {
    float a=A[0],b=A[1],c=A[2],d=A[3],e=A[4],f=A[5],g=A[6],h=A[7],i=A[8];
    float det = a*(e*i-f*h) - b*(d*i-f*g) + c*(d*h-e*g);
    float id = 1.f/det;
    out[0]=(e*i-f*h)*id; out[1]=(c*h-b*i)*id; out[2]=(b*f-c*e)*id;
    out[3]=(f*g-d*i)*id; out[4]=(a*i-c*g)*id; out[5]=(c*d-a*f)*id;
    out[6]=(d*h-e*g)*id; out[7]=(b*g-a*h)*id; out[8]=(a*e-b*d)*id;
}

__device__ void setup_body(const float* __restrict__ rotation,
                           const float* __restrict__ proj,
                           float* __restrict__ wsf) {
    float refE[16], refK[16], refNew[16], invRef[16];
    for (int k = 0; k < 16; k++) { refE[k] = proj[k]; refK[k] = proj[16+k]; }
    for (int k = 0; k < 16; k++) refNew[k] = refE[k];
    for (int r = 0; r < 3; r++) for (int c = 0; c < 4; c++) {
        float s = 0.f;
        for (int k = 0; k < 3; k++) s += refK[r*4+k] * refE[k*4+c];
        refNew[r*4+c] = s;
    }
    inv4(refNew, invRef);
    float invR0[9];
    inv3(rotation, invR0);

    for (int i = 0; i < NSRC; i++) {
        const float* E = proj + (i+1)*32;
        const float* K = proj + (i+1)*32 + 16;
        float sNew[16];
        for (int k = 0; k < 16; k++) sNew[k] = E[k];
        for (int r = 0; r < 3; r++) for (int c = 0; c < 4; c++) {
            float s = 0.f;
            for (int k = 0; k < 3; k++) s += K[r*4+k] * E[k*4+c];
            sNew[r*4+c] = s;
        }
        float P[16];
        for (int r = 0; r < 4; r++) for (int c = 0; c < 4; c++) {
            float s = 0.f;
            for (int k = 0; k < 4; k++) s += sNew[r*4+k] * invRef[k*4+c];
            P[r*4+c] = s;
        }
        float* o = wsf + 2 + i*15;
        for (int r = 0; r < 3; r++) for (int c = 0; c < 3; c++) o[r*3+c] = P[r*4+c];
        for (int r = 0; r < 3; r++) o[9+r] = P[r*4+3];
        const float* Ri = rotation + (i+1)*9;
        for (int c = 0; c < 3; c++) {
            float s = 0.f;
            for (int k = 0; k < 3; k++) s += Ri[2*3+k] * invR0[k*3+c];
            o[12+c] = s;
        }
    }
}

// Fused prep:
//  img 0..3: src [C][HW]->[HW][C];  img 4: ref;  img 5: depth (+ partial
//  min/max, plain stores -> no atomics, no memset init);  img 6: normal_plane
//  packed [HW][4]. Matrix setup rides on block (0, img0) thread 0.
__global__ __launch_bounds__(256)
void prep_kernel(const float* __restrict__ src,
                 const float* __restrict__ ref,
                 const float* __restrict__ depth,
                 const float* __restrict__ normal,
                 const float* __restrict__ rotation,
                 const float* __restrict__ proj,
                 float* __restrict__ wsf) {
    const int img = blockIdx.y;          // 0..6
    const int p0  = blockIdx.x * 64;
    const int t = threadIdx.x;

    if (img == 6) {  // normal_plane [3][HW] -> [HW][4]
        __shared__ float tl[3][64];
        if (t < 192) { const int c = t >> 6, p = t & 63; tl[c][p] = normal[c*HWc + p0 + p]; }
        __syncthreads();
        const int p = t >> 2, c = t & 3;
        wsf[NP_OFF + (size_t)(p0 + p)*4 + c] = (c < 3) ? tl[c][p] : 0.f;
        return;
    }

    const float* in = (img < NSRC) ? (src + (size_t)img*Cc*HWc)
                    : (img == NSRC) ? ref : depth;
    float* outp = wsf + T_OFF + (size_t)img * Cc * HWc;
    __shared__ float tile[Cc][64+1];
    float mn = __uint_as_float(0x7F800000u);
    float mx = 0.f;
#pragma unroll
    for (int k = 0; k < 8; k++) {
        const int c = (t >> 6) + k*4;
        const int p = t & 63;
        const float v = in[(size_t)c*HWc + p0 + p];
        tile[c][p] = v;
        mn = fminf(mn, v);
        mx = fmaxf(mx, v);
    }
    __syncthreads();
#pragma unroll
    for (int k = 0; k < 8; k++) {
        const int c = t & 31;
        const int p = (t >> 5) + k*8;
        outp[(size_t)(p0 + p)*Cc + c] = tile[c][p];
    }
    if (img == 5) {   // depth tile: partial min/max, one pair per block
        for (int off = 32; off; off >>= 1) {
            mn = fminf(mn, __shfl_xor(mn, off));
            mx = fmaxf(mx, __shfl_xor(mx, off));
        }
        __shared__ float smn[4], smx[4];
        const int w = t >> 6;
        if ((t & 63) == 0) { smn[w] = mn; smx[w] = mx; }
        __syncthreads();
        if (t == 0) {
            for (int i = 1; i < 4; i++) { mn = fminf(mn, smn[i]); mx = fmaxf(mx, smx[i]); }
            wsf[PART_OFF + blockIdx.x*2 + 0] = mn;
            wsf[PART_OFF + blockIdx.x*2 + 1] = mx;
        }
    }
    if (img == 0 && blockIdx.x == 0 && t == 0)
        setup_body(rotation, proj, wsf);
}

// Bilinear weight + pre-scaled tap-offset computation (uses Wv[0..11] only).
__device__ __forceinline__ void compute_wo(float fxp, float fyp, const float* __restrict__ Wv,
                                           float dep, float4* wout, int4* oout) {
    const float b0 = Wv[0]*fxp + Wv[1]*fyp + Wv[2];
    const float b1 = Wv[3]*fxp + Wv[4]*fyp + Wv[5];
    const float b2 = Wv[6]*fxp + Wv[7]*fyp + Wv[8];
    float z = fmaf(b2, dep, Wv[11]);
    if (z == 0.f) z = 1e-9f;
    float rz = __builtin_amdgcn_rcpf(z);
    rz = rz * (2.f - z * rz);                 // Newton refine
    const float px = fmaf(b0, dep, Wv[9])  * rz;
    const float py = fmaf(b1, dep, Wv[10]) * rz;

    const float fx0 = floorf(px), fy0 = floorf(py);
    const float wx = px - fx0, wy = py - fy0;
    const float fx1 = fx0 + 1.f, fy1 = fy0 + 1.f;
    const bool ix0 = (fx0 >= 0.f) && (fx0 <= (float)(Wc-1));
    const bool ix1 = (fx1 >= 0.f) && (fx1 <= (float)(Wc-1));
    const bool iy0 = (fy0 >= 0.f) && (fy0 <= (float)(Hc-1));
    const bool iy1 = (fy1 >= 0.f) && (fy1 <= (float)(Hc-1));
    const float w00 = (1.f-wx)*(1.f-wy) * ((ix0 && iy0) ? 1.f : 0.f);
    const float w10 = wx*(1.f-wy)       * ((ix1 && iy0) ? 1.f : 0.f);
    const float w01 = (1.f-wx)*wy       * ((ix0 && iy1) ? 1.f : 0.f);
    const float w11 = wx*wy             * ((ix1 && iy1) ? 1.f : 0.f);
    const int xi0 = (int)fminf(fmaxf(fx0, 0.f), (float)(Wc-1));
    const int xi1 = (int)fminf(fmaxf(fx1, 0.f), (float)(Wc-1));
    const int yi0 = (int)fminf(fmaxf(fy0, 0.f), (float)(Hc-1));
    const int yi1 = (int)fminf(fmaxf(fy1, 0.f), (float)(Hc-1));
    *wout = make_float4(w00, w10, w01, w11);
    *oout = make_int4((yi0*Wc + xi0)*8, (yi0*Wc + xi1)*8,
                      (yi1*Wc + xi0)*8, (yi1*Wc + xi1)*8);   // float4 units
}

// 2-pixel main kernel: 256 threads handle pixels {pix0, pix1}.
//  phase 1 (dense, all 4 waves): wave = (pixel, view-pair) weight compute;
//           wave 3 additionally reduces the 576 min/max partials (hidden).
//  phase 2: barrier-free 32-gather stream (2 px x 4 views x 4 taps, full ILP)
//  phase 3 (dense): wave = (pixel, view-pair) softmax + srcw + sims
//  phase 4: accumulate both pixels; epilogue waves 0/1 -> pixel 0/1.
template<bool USE_NPT>
__global__ __launch_bounds__(256)
void main_kernel_t(const float* __restrict__ normal_plane,
                   const float* __restrict__ w_reg,
                   const float* __restrict__ w_norm,
                   const float* __restrict__ wsf,
                   float* __restrict__ out) {
    // bijective XCD swizzle on pixel PAIRS: consecutive pairs per XCD
    const int bid = blockIdx.x;
    const int pairi = (bid & 7) * (HWc/16) + (bid >> 3);
    const int pix0 = pairi * 2;
    const int pix1 = pix0 + 1;
    const int t = threadIdx.x;
    const int g = t & 7;
    const int d = t >> 3;
    const int wv_id = t >> 6;
    const int wl = t & 63;

    const float4* srcT0 = (const float4*)(wsf + T_OFF);
    const float4* refT  = (const float4*)(wsf + T_OFF + (size_t)4*Cc*HWc);
    const float*  depT  = wsf + T_OFF + (size_t)5*Cc*HWc;

    __shared__ float4 s_wt[2][NSRC][Dc];
    __shared__ int4   s_of[2][NSRC][Dc];
    __shared__ float  s_sd[2][NSRC][Dc];
    __shared__ float  s_val[2][NSRC][Dc];
    __shared__ float  s_w[2][NSRC][Dc];
    __shared__ float  s_sw[2][NSRC][Dc];
    __shared__ float  s_hmm[2];

    // per-pixel prologue (channels-last: 1 float4 each)
    float4 rv0 = refT[pix0*8 + g];
    rv0.x *= 0.25f; rv0.y *= 0.25f; rv0.z *= 0.25f; rv0.w *= 0.25f;
    float4 rv1 = refT[pix1*8 + g];
    rv1.x *= 0.25f; rv1.y *= 0.25f; rv1.z *= 0.25f; rv1.w *= 0.25f;
    float4 npv0, npv1;
    if (USE_NPT) {
        npv0 = ((const float4*)(wsf + NP_OFF))[pix0];
        npv1 = ((const float4*)(wsf + NP_OFF))[pix1];
    } else {
        npv0 = make_float4(normal_plane[pix0], normal_plane[HWc+pix0], normal_plane[2*HWc+pix0], 0.f);
        npv1 = make_float4(normal_plane[pix1], normal_plane[HWc+pix1], normal_plane[2*HWc+pix1], 0.f);
    }
    const float dep_d0 = depT[(size_t)pix0*Dc + d];
    const float dep_d1 = depT[(size_t)pix1*Dc + d];
    const float wreg_g = w_reg[g];

    // ---- phase 1 (dense): wave -> (pixel, view-pair); wave3 += minmax ----
    {
        const int px = wv_id >> 1;
        const int v0 = (wv_id & 1) << 1;
        const int vv = v0 | (wl >> 5);
        const int dd = wl & 31;
        const int pixp = px ? pix1 : pix0;
        const float fx = (float)(pixp % Wc);
        const float fy = (float)(pixp / Wc);
        const float* Wa = wsf + 2 + v0*15;
        const float* Wb = Wa + 15;
        float Wv[12];
#pragma unroll
        for (int k = 0; k < 12; k++) Wv[k] = (wl < 32) ? Wa[k] : Wb[k];
        compute_wo(fx, fy, Wv, depT[(size_t)pixp*Dc + dd],
                   &s_wt[px][vv][dd], &s_of[px][vv][dd]);
        if (wv_id == 3) {   // reduce 576 partial (min,max) pairs, hidden here
            float mn = __uint_as_float(0x7F800000u);
            float mx = 0.f;
#pragma unroll
            for (int j = 0; j < 9; j++) {   // 576 = 64*9
                mn = fminf(mn, wsf[PART_OFF + (wl + 64*j)*2 + 0]);
                mx = fmaxf(mx, wsf[PART_OFF + (wl + 64*j)*2 + 1]);
            }
            for (int off = 32; off; off >>= 1) {
                mn = fminf(mn, __shfl_xor(mn, off));
                mx = fmaxf(mx, __shfl_xor(mx, off));
            }
            if (wl == 0) { s_hmm[0] = mn; s_hmm[1] = mx; }
        }
    }
    __syncthreads();

    // ---- phase 2: barrier-free gather + blend stream (both pixels) ----
    float corfeat[2][NSRC];
#pragma unroll
    for (int px = 0; px < 2; px++) {
        const float4 rvp = px ? rv1 : rv0;
#pragma unroll
        for (int i = 0; i < NSRC; i++) {
            const float4 wv = s_wt[px][i][d];
            const int4   ov = s_of[px][i][d];
            const float4* sp = srcT0 + (size_t)i*HWc*8 + g;
            const float4 v00 = sp[ov.x];
            const float4 v10 = sp[ov.y];
            const float4 v01 = sp[ov.z];
            const float4 v11 = sp[ov.w];
            const float bx = wv.x*v00.x + wv.y*v10.x + wv.z*v01.x + wv.w*v11.x;
            const float by = wv.x*v00.y + wv.y*v10.y + wv.z*v01.y + wv.w*v11.y;
            const float bz = wv.x*v00.z + wv.y*v10.z + wv.z*v01.z + wv.w*v11.z;
            const float bw = wv.x*v00.w + wv.y*v10.w + wv.z*v01.w + wv.w*v11.w;
            corfeat[px][i] = bx*rvp.x + by*rvp.y + bz*rvp.z + bw*rvp.w;

            float sd = corfeat[px][i];
            sd += __shfl_xor(sd, 1);
            sd += __shfl_xor(sd, 2);
            sd += __shfl_xor(sd, 4);

            if (g == 0) { s_sd[px][i][d] = sd; s_val[px][i][d] = (bx != 0.f) ? 1.f : 0.f; }
        }
    }
    __syncthreads();

    // ---- phase 3 (dense): wave -> (pixel, view-pair) softmax + srcw ----
    {
        const int px = wv_id >> 1;
        const int v0 = (wv_id & 1) << 1;
        const int vv = v0 | (wl >> 5);
        const int dd = wl & 31;
        const int pixp = px ? pix1 : pix0;
        const float4 npv = px ? npv1 : npv0;

        const float u = s_sd[px][vv][dd];
        float m = u;
        for (int off = 1; off < 32; off <<= 1) m = fmaxf(m, __shfl_xor(m, off));
        const float e = __expf(u - m);
        float se = e;
        for (int off = 1; off < 32; off <<= 1) se += __shfl_xor(se, off);
        float rse = __builtin_amdgcn_rcpf(se);
        rse = rse * (2.f - se * rse);
        s_w[px][vv][dd] = e * rse * 0.17677669529663687f;  // softmax / sqrt(C)

        const float* Na = wsf + 2 + v0*15 + 12;
        const float* Nb = Na + 15;
        const float n0 = (wl < 32) ? Na[0] : Nb[0];
        const float n1 = (wl < 32) ? Na[1] : Nb[1];
        const float n2 = (wl < 32) ? Na[2] : Nb[2];
        const float srcw_v = fmaxf(npv.x*n0 + npv.y*n1 + npv.z*n2, 0.f) + 0.01f;
        const float swv = srcw_v * s_val[px][vv][dd];
        s_sw[px][vv][dd] = swv;
        float ss = swv;
        for (int off = 1; off < 32; off <<= 1) ss += __shfl_xor(ss, off);
        if ((wl & 31) == 0) out[OFF_WEIGHT + vv*HWc + pixp] = ss * (1.f/32.f);
    }
    __syncthreads();

    // ---- phase 4: accumulate + finalize logits (both pixels) ----
    const float hmin = s_hmm[0];
    const float hmax = s_hmm[1];
    const float hr = hmax - hmin;
    float rhr = __builtin_amdgcn_rcpf(hr);
    rhr = rhr * (2.f - hr * rhr);

    float sumw_keep0 = 0.f, sumw_keep1 = 0.f;
#pragma unroll
    for (int px = 0; px < 2; px++) {
        float acc_cor = 0.f;
        float cws_acc = 1e-8f;
        float sumw_acc = 1e-8f;
#pragma unroll
        for (int i = 0; i < NSRC; i++) {
            const float cor_w = s_w[px][i][d];
            const float sw = s_sw[px][i][d];
            acc_cor = fmaf(cor_w * sw, corfeat[px][i], acc_cor);
            cws_acc += cor_w;
            sumw_acc += sw;
        }
        float r1 = __builtin_amdgcn_rcpf(sumw_acc);
        r1 = r1 * (2.f - sumw_acc * r1);
        float r2 = __builtin_amdgcn_rcpf(cws_acc);
        r2 = r2 * (2.f - cws_acc * r2);
        const float cf_final = acc_cor * r1 * r2;
        float part = cf_final * wreg_g;
        part += __shfl_xor(part, 1);
        part += __shfl_xor(part, 2);
        part += __shfl_xor(part, 4);
        const float dd_ = px ? dep_d1 : dep_d0;
        const float logit = part + (dd_ - hmin) * rhr;
        if (g == 0) s_sd[px][0][d] = logit;
        if (px == 0) sumw_keep0 = sumw_acc; else sumw_keep1 = sumw_acc;
    }
    if (t == 0) {
        out[OFF_SW + pix0] = sumw_keep0 * 0.25f;   // d==0 lane, /nsrc
        out[OFF_SW + pix1] = sumw_keep1 * 0.25f;
    }
    __syncthreads();

    // ---- epilogue: wave 0 -> pixel 0, wave 1 -> pixel 1 (lower 32 lanes) ----
    if (wv_id < 2 && wl < 32) {
        const int px = wv_id;
        const int pixp = px ? pix1 : pix0;
        const int tt = wl;
        const float L = s_sd[px][0][tt];
        float m = L;
        for (int off = 1; off < 32; off <<= 1) m = fmaxf(m, __shfl_xor(m, off));
        const float e = __expf(L - m);
        float se = e;
        for (int off = 1; off < 32; off <<= 1) se += __shfl_xor(se, off);
        float rse = __builtin_amdgcn_rcpf(se);
        rse = rse * (2.f - se * rse);
        const float attn = e * rse;

        const float nval = s_val[px][0][tt] + s_val[px][1][tt]
                         + s_val[px][2][tt] + s_val[px][3][tt];
        out[OFF_ATTN + tt*HWc + pixp] = attn;
        out[OFF_NVAL + tt*HWc + pixp] = nval;

        float av = attn; int ai = tt;
        for (int off = 1; off < 32; off <<= 1) {
            float av2 = __shfl_xor(av, off);
            int ai2 = __shfl_xor(ai, off);
            if (av2 > av || (av2 == av && ai2 < ai)) { av = av2; ai = ai2; }
        }
        const float dep = depT[(size_t)pixp*Dc + tt];
        const float dep_sel = __shfl(dep, ai);
        const float dep0 = __shfl(dep, 0);
        const float dep1 = __shfl(dep, 1);
        if (tt == 0) {
            const float last_itv = dep1 - dep0;
            out[OFF_DEPTH + pixp] = dep_sel;
            out[OFF_CONF + pixp] = av;
            out[OFF_MIN + pixp] = dep_sel - last_itv;
            out[OFF_MAX + pixp] = dep_sel + last_itv;
        }
    }
    if (wv_id < 2 && wl < 3) {
        const int px = wv_id;
        const int pixp = px ? pix1 : pix0;
        const float4 npv = px ? npv1 : npv0;
        float v = npv.x*w_norm[wl*3+0] + npv.y*w_norm[wl*3+1] + npv.z*w_norm[wl*3+2];
        out[OFF_EST + wl*HWc + pixp] = v;
    }
}

// ---------------- fallback path (original, untransposed) ----------------
__global__ void setup_kernel_fb(const float* __restrict__ rotation,
                                const float* __restrict__ proj,
                                float* __restrict__ wsf) {
    if (threadIdx.x != 0 || blockIdx.x != 0) return;
    unsigned int* wsu = (unsigned int*)wsf;
    wsu[0] = 0x7F800000u;
    wsu[1] = 0u;
    setup_body(rotation, proj, wsf);
}

__global__ __launch_bounds__(256)
void minmax_kernel_fb(const float* __restrict__ depth, unsigned int* __restrict__ wsu) {
    const int tid = blockIdx.x * blockDim.x + threadIdx.x;
    const int stride = gridDim.x * blockDim.x;
    const int n4 = (Dc*HWc) / 4;
    const float4* d4 = (const float4*)depth;
    float mn = __uint_as_float(0x7F800000u);
    float mx = 0.f;
    for (int idx = tid; idx < n4; idx += stride) {
        float4 v = d4[idx];
        mn = fminf(mn, fminf(fminf(v.x, v.y), fminf(v.z, v.w)));
        mx = fmaxf(mx, fmaxf(fmaxf(v.x, v.y), fmaxf(v.z, v.w)));
    }
    for (int off = 32; off; off >>= 1) {
        mn = fminf(mn, __shfl_xor(mn, off));
        mx = fmaxf(mx, __shfl_xor(mx, off));
    }
    __shared__ float smn[4], smx[4];
    const int w = threadIdx.x >> 6;
    if ((threadIdx.x & 63) == 0) { smn[w] = mn; smx[w] = mx; }
    __syncthreads();
    if (threadIdx.x == 0) {
        for (int i = 1; i < 4; i++) { mn = fminf(mn, smn[i]); mx = fmaxf(mx, smx[i]); }
        atomicMin(&wsu[0], __float_as_uint(mn));
        atomicMax(&wsu[1], __float_as_uint(mx));
    }
}

__global__ __launch_bounds__(256)
void main_kernel(const float* __restrict__ ref_feature,
                 const float* __restrict__ src_features,
                 const float* __restrict__ normal_plane,
                 const float* __restrict__ depth_hypo,
                 const float* __restrict__ w_reg,
                 const float* __restrict__ w_norm,
                 const float* __restrict__ wsf,
                 float* __restrict__ out) {
    const int pix = blockIdx.x;
    const int t = threadIdx.x;
    const int d = t & 31;
    const int g = t >> 5;
    const float fxp = (float)(pix % Wc);
    const float fyp = (float)(pix / Wc);

    __shared__ float s_cf[Gc*Dc];
    __shared__ float s_valid[Dc];

    float refv[4];
#pragma unroll
    for (int j = 0; j < 4; j++) refv[j] = ref_feature[(g*4+j)*HWc + pix];
    const float np0 = normal_plane[0*HWc + pix];
    const float np1 = normal_plane[1*HWc + pix];
    const float np2 = normal_plane[2*HWc + pix];
    const float depth_d = depth_hypo[d*HWc + pix];
    const float wreg_g = w_reg[g];

    float acc_cor = 0.f;
    float cws_acc = 1e-8f;
    float sumw_acc = 1e-8f;
    float nval_acc = 0.f;

    for (int i = 0; i < NSRC; i++) {
        const float* Wv = wsf + 2 + i*15;
        const float r00=Wv[0], r01=Wv[1], r02=Wv[2];
        const float r10=Wv[3], r11=Wv[4], r12=Wv[5];
        const float r20=Wv[6], r21=Wv[7], r22=Wv[8];
        const float t0=Wv[9], t1=Wv[10], t2=Wv[11];
        const float nv0=Wv[12], nv1=Wv[13], nv2=Wv[14];

        const float b0 = r00*fxp + r01*fyp + r02;
        const float b1 = r10*fxp + r11*fyp + r12;
        const float b2 = r20*fxp + r21*fyp + r22;

        float z = b2*depth_d + t2;
        if (z == 0.f) z = 1e-9f;
        const float px = (b0*depth_d + t0) / z;
        const float py = (b1*depth_d + t1) / z;

        const float fx0 = floorf(px), fy0 = floorf(py);
        const float wx = px - fx0, wy = py - fy0;
        const float fx1 = fx0 + 1.f, fy1 = fy0 + 1.f;
        const bool ix0 = (fx0 >= 0.f) && (fx0 <= (float)(Wc-1));
        const bool ix1 = (fx1 >= 0.f) && (fx1 <= (float)(Wc-1));
        const bool iy0 = (fy0 >= 0.f) && (fy0 <= (float)(Hc-1));
        const bool iy1 = (fy1 >= 0.f) && (fy1 <= (float)(Hc-1));
        const float w00 = (1.f-wx)*(1.f-wy) * ((ix0 && iy0) ? 1.f : 0.f);
        const float w10 = wx*(1.f-wy)       * ((ix1 && iy0) ? 1.f : 0.f);
        const float w01 = (1.f-wx)*wy       * ((ix0 && iy1) ? 1.f : 0.f);
        const float w11 = wx*wy             * ((ix1 && iy1) ? 1.f : 0.f);
        const int xi0 = (int)fminf(fmaxf(fx0, 0.f), (float)(Wc-1));
        const int xi1 = (int)fminf(fmaxf(fx1, 0.f), (float)(Wc-1));
        const int yi0 = (int)fminf(fmaxf(fy0, 0.f), (float)(Hc-1));
        const int yi1 = (int)fminf(fmaxf(fy1, 0.f), (float)(Hc-1));
        const int o00 = yi0*Wc + xi0, o10 = yi0*Wc + xi1;
        const int o01 = yi1*Wc + xi0, o11 = yi1*Wc + xi1;

        const float* src = src_features + (size_t)i * Cc * HWc;
        float corfeat = 0.f;
        float warp0 = 0.f;
#pragma unroll
        for (int j = 0; j < 4; j++) {
            const float* sc = src + (g*4 + j) * HWc;
            float v = w00*sc[o00] + w10*sc[o10] + w01*sc[o01] + w11*sc[o11];
            if (j == 0) warp0 = v;
            corfeat += v * refv[j];
        }
        corfeat *= 0.25f;

        s_cf[t] = corfeat;
        if (g == 0) s_valid[d] = (warp0 != 0.f) ? 1.f : 0.f;
        __syncthreads();

        float s_d = 0.f;
#pragma unroll
        for (int gg = 0; gg < Gc; gg++) s_d += s_cf[gg*32 + d];
        float m = s_d;
        for (int off = 1; off < 32; off <<= 1) m = fmaxf(m, __shfl_xor(m, off));
        float e = expf(s_d - m);
        float se = e;
        for (int off = 1; off < 32; off <<= 1) se += __shfl_xor(se, off);
        const float cor_w = (e / se) * 0.17677669529663687f;

        const float valid = s_valid[d];
        const float src_w = fmaxf(np0*nv0 + np1*nv1 + np2*nv2, 0.f) + 0.01f;
        const float sw = src_w * valid;

        acc_cor += cor_w * sw * corfeat;
        cws_acc += cor_w;
        sumw_acc += sw;
        nval_acc += valid;

        float ssum = sw;
        for (int off = 1; off < 32; off <<= 1) ssum += __shfl_xor(ssum, off);
        if (t == 0) out[OFF_WEIGHT + i*HWc + pix] = ssum * (1.f/32.f);
        __syncthreads();
    }

    const float cf_final = acc_cor / sumw_acc / cws_acc;
    s_cf[t] = cf_final * wreg_g;
    __syncthreads();
    float logit = 0.f;
#pragma unroll
    for (int gg = 0; gg < Gc; gg++) logit += s_cf[gg*32 + d];

    const unsigned int* wsu = (const unsigned int*)wsf;
    const float hmin = __uint_as_float(wsu[0]);
    const float hmax = __uint_as_float(wsu[1]);
    logit += (depth_d - hmin) / (hmax - hmin);

    float m = logit;
    for (int off = 1; off < 32; off <<= 1) m = fmaxf(m, __shfl_xor(m, off));
    float e = expf(logit - m);
    float se = e;
    for (int off = 1; off < 32; off <<= 1) se += __shfl_xor(se, off);
    const float attn = e / se;

    float av = attn; int ai = d;
    for (int off = 1; off < 32; off <<= 1) {
        float av2 = __shfl_xor(av, off);
        int ai2 = __shfl_xor(ai, off);
        if (av2 > av || (av2 == av && ai2 < ai)) { av = av2; ai = ai2; }
    }
    const float dep_sel = __shfl(depth_d, ai, 32);
    const float dep0 = __shfl(depth_d, 0, 32);
    const float dep1 = __shfl(depth_d, 1, 32);
    const float last_itv = dep1 - dep0;

    if (t < 32) {
        out[OFF_ATTN + d*HWc + pix] = attn;
        out[OFF_NVAL + d*HWc + pix] = nval_acc;
    }
    if (t == 0) {
        out[OFF_DEPTH + pix] = dep_sel;
        out[OFF_CONF + pix] = av;
        out[OFF_SW + pix] = sumw_acc * 0.25f;
        out[OFF_MIN + pix] = dep_sel - last_itv;
        out[OFF_MAX + pix] = dep_sel + last_itv;
    }
    if (t < 3) {
        float v = np0*w_norm[t*3+0] + np1*w_norm[t*3+1] + np2*w_norm[t*3+2];
        out[OFF_EST + t*HWc + pix] = v;
    }
}

extern "C" void kernel_launch(void* const* d_in, const int* in_sizes, int n_in,
                              void* d_out, int out_size, void* d_ws, size_t ws_size,
                              hipStream_t stream) {
    const float* ref   = (const float*)d_in[0];
    const float* src   = (const float*)d_in[1];
    const float* rot   = (const float*)d_in[2];
    const float* np_   = (const float*)d_in[3];
    const float* proj  = (const float*)d_in[4];
    const float* dh    = (const float*)d_in[5];
    const float* wreg  = (const float*)d_in[6];
    const float* wnorm = (const float*)d_in[7];
    float* out = (float*)d_out;
    float* ws  = (float*)d_ws;

    const size_t need_np   = (size_t)(NP_OFF + 4*HWc) * sizeof(float);
    const size_t need_base = (size_t)NP_OFF * sizeof(float);

    if (ws_size >= need_np) {
        dim3 tg(NTILE, 7);
        prep_kernel<<<tg, 256, 0, stream>>>(src, ref, dh, np_, rot, proj, ws);
        main_kernel_t<true><<<HWc/2, 256, 0, stream>>>(np_, wreg, wnorm, ws, out);
    } else if (ws_size >= need_base) {
        dim3 tg(NTILE, 6);
        prep_kernel<<<tg, 256, 0, stream>>>(src, ref, dh, np_, rot, proj, ws);
        main_kernel_t<false><<<HWc/2, 256, 0, stream>>>(np_, wreg, wnorm, ws, out);
    } else {
        hipMemsetAsync((char*)d_ws + 0, 0xFF, 4, stream);
        hipMemsetAsync((char*)d_ws + 4, 0x00, 4, stream);
        setup_kernel_fb<<<1, 1, 0, stream>>>(rot, proj, ws);
        minmax_kernel_fb<<<64, 256, 0, stream>>>(dh, (unsigned int*)ws);
        main_kernel<<<HWc, 256, 0, stream>>>(ref, src, np_, dh, wreg, wnorm, ws, out);
    }
}